// Round 1
// baseline (1151.102 us; speedup 1.0000x reference)
//
#include <hip/hip_runtime.h>

#define B_  4096
#define T_  32
#define M_  131072   // B*T

typedef unsigned short u16;
typedef short bf16x8 __attribute__((ext_vector_type(8)));
typedef float f32x4 __attribute__((ext_vector_type(4)));

__device__ __forceinline__ float bf2f(u16 v){
  union { unsigned u; float f; } x; x.u = ((unsigned)v) << 16; return x.f;
}
__device__ __forceinline__ u16 f2bf(float f){
  union { float f; unsigned u; } x; x.f = f;
  unsigned u = x.u;
  u += 0x7fffu + ((u >> 16) & 1u);
  return (u16)(u >> 16);
}
__device__ __forceinline__ float sigm(float x){ return 1.f/(1.f+__expf(-x)); }
__device__ __forceinline__ float tanh_s(float x){ return 1.f - 2.f/(__expf(2.f*x)+1.f); }
__device__ __forceinline__ f32x4 mfma16(bf16x8 a, bf16x8 b, f32x4 c){
  return __builtin_amdgcn_mfma_f32_16x16x32_bf16(a, b, c, 0, 0, 0);
}
__device__ __forceinline__ void gl2lds16(const void* g, void* l){
  __builtin_amdgcn_global_load_lds(
      (const __attribute__((address_space(1))) unsigned int*)g,
      (__attribute__((address_space(3))) unsigned int*)l, 16, 0, 0);
}

// ---------------- prep: weights -> bf16 (+ layout splits) ----------------
__global__ void prep_w(const float* __restrict__ W_ih, const float* __restrict__ W_hh,
                       const float* __restrict__ Wph, const float* __restrict__ Woh,
                       const float* __restrict__ Wpm, const float* __restrict__ Wps,
                       const float* __restrict__ Wqm, const float* __restrict__ Wqs,
                       const float* __restrict__ Wg,  const float* __restrict__ bph,
                       const float* __restrict__ boh,
                       u16* __restrict__ wsb, float* __restrict__ Woy, float* __restrict__ bpq)
{
  int idx = blockIdx.x*256 + threadIdx.x;
  if (idx < 196608){ wsb[idx] = f2bf(W_ih[idx]); return; }
  if (idx < 393216){ wsb[idx] = f2bf(W_hh[idx-196608]); return; }
  if (idx < 524288){ int j = idx-393216; int row = j>>9, col = j&511;
    float v = (row<128) ? Wph[row*640+col] : Woh[(row-128)*642+col];
    wsb[idx] = f2bf(v); return; }
  if (idx < 540672){ int j = idx-524288; int row=j>>7, col=j&127; wsb[idx]=f2bf(Wph[row*640+512+col]); return; }
  if (idx < 557056){ int j = idx-540672; int row=j>>7, col=j&127; wsb[idx]=f2bf(Woh[row*642+514+col]); return; }
  if (idx < 573440){ wsb[idx]=f2bf(Wpm[idx-557056]); return; }
  if (idx < 589824){ wsb[idx]=f2bf(Wps[idx-573440]); return; }
  if (idx < 606208){ wsb[idx]=f2bf(Wqm[idx-589824]); return; }
  if (idx < 622592){ wsb[idx]=f2bf(Wqs[idx-606208]); return; }
  if (idx < 671744){ wsb[idx]=f2bf(Wg[idx-622592]); return; }
  if (idx < 672000){ int j = idx-671744; int row=j>>1; Woy[j] = Woh[row*642+512+(j&1)]; return; }
  if (idx < 672256){ int j = idx-672000; bpq[j] = (j<128) ? bph[j] : boh[j-128]; return; }
}

__global__ void prep_x(const float* __restrict__ x, u16* __restrict__ xbf){
  int i = blockIdx.x*256 + threadIdx.x;
  if (i >= 4194304) return;
  const float4* src = (const float4*)(x + (size_t)i*8);
  float4 a = src[0], b = src[1];
  uint4 o;
  o.x = (unsigned)f2bf(a.x) | ((unsigned)f2bf(a.y)<<16);
  o.y = (unsigned)f2bf(a.z) | ((unsigned)f2bf(a.w)<<16);
  o.z = (unsigned)f2bf(b.x) | ((unsigned)f2bf(b.y)<<16);
  o.w = (unsigned)f2bf(b.z) | ((unsigned)f2bf(b.w)<<16);
  ((uint4*)xbf)[i] = o;
}

// ---------------- generic C = A@W^T + bias (A may be [A1|A2] along K) ----------------
// grid (M/128, N/256), block 512.  C bf16 [M][N].
__global__ __launch_bounds__(512, 4) void gemm_bt(
  const u16* __restrict__ A1, const u16* __restrict__ A2, int K1, int Ktot,
  const u16* __restrict__ W, const float* __restrict__ bias,
  u16* __restrict__ C, int N, int mode,
  const float* __restrict__ yt, const float* __restrict__ Woy)
{
  const int m0 = blockIdx.x*128;
  const int n0 = blockIdx.y*256;
  const int tid = threadIdx.x;
  const int w = tid>>6, lane = tid&63, c = lane&15, g = lane>>4;
  const int wm = w>>2, wn = w&3;
  const int K2 = Ktot - K1;
  __shared__ __align__(16) u16 abuf[8*128*8];   // [k8][row][8]
  __shared__ __align__(16) u16 wbuf[8*256*8];   // [k8][row][8]
  f32x4 acc[4][4];
  #pragma unroll
  for (int i=0;i<4;++i)
    #pragma unroll
    for (int j=0;j<4;++j) acc[i][j] = (f32x4){0.f,0.f,0.f,0.f};
  const int nch = Ktot >> 6;
  for (int kc=0; kc<nch; ++kc){
    __syncthreads();                       // prev chunk fully consumed
    #pragma unroll
    for (int i=0;i<2;++i){                 // A pieces
      int ii = w*2 + i;
      int p = ii*64 + lane;
      int k8 = p>>7, row = p&127;
      int k = (kc<<6) + k8*8;
      const u16* src = (k < K1) ? (A1 + (size_t)(m0+row)*K1 + k)
                                : (A2 + (size_t)(m0+row)*K2 + (k-K1));
      gl2lds16(src, &abuf[ii*512]);
    }
    #pragma unroll
    for (int i=0;i<4;++i){                 // W pieces
      int ii = w*4 + i;
      int p = ii*64 + lane;
      int k8 = p>>8, row = p&255;
      int k = (kc<<6) + k8*8;
      const u16* src = W + (size_t)(n0+row)*Ktot + k;
      gl2lds16(src, &wbuf[ii*512]);
    }
    __syncthreads();                       // drains vmcnt -> data in LDS
    #pragma unroll
    for (int ks=0;ks<2;++ks){
      int k8 = ks*4 + g;
      bf16x8 a[4];
      #pragma unroll
      for (int mt=0;mt<4;++mt) a[mt] = *(const bf16x8*)&abuf[(k8*128 + wm*64 + mt*16 + c)*8];
      #pragma unroll
      for (int nt=0;nt<4;++nt){
        bf16x8 b = *(const bf16x8*)&wbuf[(k8*256 + wn*64 + nt*16 + c)*8];
        #pragma unroll
        for (int mt=0;mt<4;++mt)
          acc[mt][nt] = mfma16(a[mt], b, acc[mt][nt]);
      }
    }
  }
  #pragma unroll
  for (int nt=0;nt<4;++nt){
    int n = n0 + wn*64 + nt*16 + c;
    float bn = bias[n];
    float wy0 = 0.f, wy1 = 0.f;
    bool yfl = (mode==1) && (n >= 128);
    if (yfl){ wy0 = Woy[(n-128)*2]; wy1 = Woy[(n-128)*2+1]; }
    #pragma unroll
    for (int mt=0;mt<4;++mt){
      #pragma unroll
      for (int r=0;r<4;++r){
        size_t m = (size_t)m0 + wm*64 + mt*16 + g*4 + r;
        float v = acc[mt][nt][r] + bn;
        if (yfl) v += yt[2*m]*wy0 + yt[2*m+1]*wy1;
        C[m*(size_t)N + n] = f2bf(v);
      }
    }
  }
}

// ---------------- sequential GRU over T, streaming W_hh ----------------
// 128 blocks x 512 threads, 32 batch rows/block. Gate-aligned wave columns.
__global__ __launch_bounds__(512, 2) void gru_seq(
  const u16* __restrict__ GI, const u16* __restrict__ Whh,
  const float* __restrict__ bhh, const int* __restrict__ n_days,
  u16* __restrict__ hs)
{
  const int b0 = blockIdx.x*32;
  const int tid = threadIdx.x;
  const int w = tid>>6, lane = tid&63, c = lane&15, g = lane>>4;
  __shared__ __align__(16) u16 hbuf[32*32*8];     // h: [k8 32][row 32][8]
  __shared__ __align__(16) u16 wbuf[8*2*3072];    // per-wave private dbuf: [w][buf][k8 4][rloc 96][8]
  float bhr[2], bhu[2], bhn[2];
  #pragma unroll
  for (int s=0;s<2;++s){
    int j = w*32 + s*16 + c;
    bhr[s] = bhh[j]; bhu[s] = bhh[256+j]; bhn[s] = bhh[512+j];
  }
  int nd[2][4];
  #pragma unroll
  for (int mt=0;mt<2;++mt)
    #pragma unroll
    for (int r=0;r<4;++r) nd[mt][r] = n_days[b0 + mt*16 + g*4 + r];
  int grow[6], k8s[6];
  #pragma unroll
  for (int j=0;j<6;++j){
    int p = j*64 + lane;
    int k8 = p/96;
    int rl = p - k8*96;
    int gr = (rl<32) ? (w*32+rl) : (rl<64) ? (256+w*32+rl-32) : (512+w*32+rl-64);
    grow[j]=gr; k8s[j]=k8;
  }
  float hreg[2][2][4];
  #pragma unroll
  for (int s=0;s<2;++s)
    #pragma unroll
    for (int mt=0;mt<2;++mt)
      #pragma unroll
      for (int r=0;r<4;++r) hreg[s][mt][r]=0.f;
  for (int i=tid; i<1024; i+=512) ((uint4*)hbuf)[i] = make_uint4(0,0,0,0);
  __syncthreads();
  u16* wslice = &wbuf[w*2*3072];

  for (int t=0;t<32;++t){
    f32x4 aRU[2][2][2], aHN[2][2];
    #pragma unroll
    for (int s=0;s<2;++s)
      #pragma unroll
      for (int mt=0;mt<2;++mt){
        aRU[0][s][mt] = (f32x4){bhr[s],bhr[s],bhr[s],bhr[s]};
        aRU[1][s][mt] = (f32x4){bhu[s],bhu[s],bhu[s],bhu[s]};
        aHN[s][mt]    = (f32x4){bhn[s],bhn[s],bhn[s],bhn[s]};
      }
    // prologue: chunks 0,1 into private dbuf (6 x 1KB each)
    #pragma unroll
    for (int j=0;j<6;++j) gl2lds16(Whh + (size_t)grow[j]*256 + 0*32 + k8s[j]*8, &wslice[0*3072 + j*512]);
    #pragma unroll
    for (int j=0;j<6;++j) gl2lds16(Whh + (size_t)grow[j]*256 + 1*32 + k8s[j]*8, &wslice[1*3072 + j*512]);
    #pragma unroll
    for (int p=0;p<8;++p){
      if (p<7) { asm volatile("s_waitcnt vmcnt(6)" ::: "memory"); }
      else     { asm volatile("s_waitcnt vmcnt(0)" ::: "memory"); }
      __builtin_amdgcn_sched_barrier(0);
      bf16x8 a[2];
      #pragma unroll
      for (int mt=0;mt<2;++mt) a[mt] = *(const bf16x8*)&hbuf[((p*4+g)*32 + mt*16 + c)*8];
      const u16* wb = &wslice[(p&1)*3072];
      #pragma unroll
      for (int nt=0;nt<6;++nt){
        bf16x8 b = *(const bf16x8*)&wb[(g*96 + nt*16 + c)*8];
        const int gate = nt>>1, s = nt&1;
        #pragma unroll
        for (int mt=0;mt<2;++mt){
          if (gate==0)      aRU[0][s][mt] = mfma16(a[mt], b, aRU[0][s][mt]);
          else if (gate==1) aRU[1][s][mt] = mfma16(a[mt], b, aRU[1][s][mt]);
          else              aHN[s][mt]    = mfma16(a[mt], b, aHN[s][mt]);
        }
      }
      if (p<6){
        __builtin_amdgcn_sched_barrier(0);
        const int q = p+2;
        #pragma unroll
        for (int j=0;j<6;++j)
          gl2lds16(Whh + (size_t)grow[j]*256 + q*32 + k8s[j]*8, &wslice[(p&1)*3072 + j*512]);
      }
    }
    __syncthreads();    // all waves done reading hbuf before rewrite
    #pragma unroll
    for (int s=0;s<2;++s){
      const int j = w*32 + s*16 + c;
      #pragma unroll
      for (int mt=0;mt<2;++mt){
        #pragma unroll
        for (int r=0;r<4;++r){
          size_t m = (size_t)(b0 + mt*16 + g*4 + r)*32 + t;
          const u16* gp = GI + m*768;
          float gir = bf2f(gp[j]);
          float giu = bf2f(gp[256+j]);
          float gin = bf2f(gp[512+j]);
          float rr = sigm(gir + aRU[0][s][mt][r]);
          float uu = sigm(giu + aRU[1][s][mt][r]);
          float nn = tanh_s(gin + rr*aHN[s][mt][r]);
          float h = (1.f-uu)*nn + uu*hreg[s][mt][r];
          hreg[s][mt][r] = h;
          u16 hb = f2bf(h);
          hs[m*256 + j] = (t < nd[mt][r]) ? hb : (u16)0;
          hbuf[((j>>3)*32 + mt*16 + g*4 + r)*8 + (j&7)] = hb;
        }
      }
    }
    __syncthreads();    // hbuf visible for next step
  }
}

// ---------------- sequential VAE scan; 6 ZxZ mats register-resident ----------------
__global__ __launch_bounds__(512, 2) void vae_seq(
  const u16* __restrict__ HPQ, const float* __restrict__ z0,
  const float* __restrict__ eps, const int* __restrict__ n_days,
  const u16* __restrict__ Wm,
  const float* __restrict__ bpm, const float* __restrict__ bps,
  const float* __restrict__ bqm, const float* __restrict__ bqs,
  u16* __restrict__ zidx, float* __restrict__ out)
{
  const int b0 = blockIdx.x*16;
  const int tid = threadIdx.x, w = tid>>6, lane = tid&63, c = lane&15, g = lane>>4;
  __shared__ __align__(16) u16 zbuf[16*16*8];
  __shared__ __align__(16) u16 hzp[16*16*8];
  __shared__ __align__(16) u16 hzq[16*16*8];
  __shared__ float klbuf[16][8];
  bf16x8 wf[6][4];
  #pragma unroll
  for (int mat=0;mat<6;++mat)
    #pragma unroll
    for (int ks=0;ks<4;++ks)
      wf[mat][ks] = *(const bf16x8*)&Wm[mat*16384 + (w*16+c)*128 + ks*32 + g*8];
  const int col = w*16 + c;
  const float bpm_l = bpm[col], bps_l = bps[col], bqm_l = bqm[col], bqs_l = bqs[col];
  int nd4[4];
  #pragma unroll
  for (int r=0;r<4;++r) nd4[r] = n_days[b0 + g*4 + r];
  if (tid < 256){
    int k8 = tid>>4, row = tid&15;
    const float* zp = z0 + (size_t)(b0+row)*128 + k8*8;
    uint4 o;
    o.x = (unsigned)f2bf(zp[0]) | ((unsigned)f2bf(zp[1])<<16);
    o.y = (unsigned)f2bf(zp[2]) | ((unsigned)f2bf(zp[3])<<16);
    o.z = (unsigned)f2bf(zp[4]) | ((unsigned)f2bf(zp[5])<<16);
    o.w = (unsigned)f2bf(zp[6]) | ((unsigned)f2bf(zp[7])<<16);
    ((uint4*)zbuf)[tid] = o;
  }
  __syncthreads();
  for (int t=0;t<32;++t){
    f32x4 accP = (f32x4){0,0,0,0}, accQ = (f32x4){0,0,0,0};
    #pragma unroll
    for (int ks=0;ks<4;++ks){
      bf16x8 az = *(const bf16x8*)&zbuf[((ks*4+g)*16 + c)*8];
      accP = mfma16(az, wf[0][ks], accP);
      accQ = mfma16(az, wf[1][ks], accQ);
    }
    #pragma unroll
    for (int r=0;r<4;++r){
      size_t m = (size_t)(b0 + g*4 + r)*32 + t;
      float hp = bf2f(HPQ[m*256 + col]) + accP[r];
      float hq = bf2f(HPQ[m*256 + 128 + col]) + accQ[r];
      int li = ((col>>3)*16 + g*4 + r)*8 + (col&7);
      hzp[li] = f2bf(tanh_s(hp));
      hzq[li] = f2bf(tanh_s(hq));
    }
    __syncthreads();
    f32x4 aMP=(f32x4){0,0,0,0}, aAP=(f32x4){0,0,0,0}, aMQ=(f32x4){0,0,0,0}, aAQ=(f32x4){0,0,0,0};
    #pragma unroll
    for (int ks=0;ks<4;++ks){
      bf16x8 ap_ = *(const bf16x8*)&hzp[((ks*4+g)*16 + c)*8];
      bf16x8 aq_ = *(const bf16x8*)&hzq[((ks*4+g)*16 + c)*8];
      aMP = mfma16(ap_, wf[2][ks], aMP);
      aAP = mfma16(ap_, wf[3][ks], aAP);
      aMQ = mfma16(aq_, wf[4][ks], aMQ);
      aAQ = mfma16(aq_, wf[5][ks], aAQ);
    }
    float kl[4];
    #pragma unroll
    for (int r=0;r<4;++r){
      float mp = aMP[r]+bpm_l, ap = aAP[r]+bps_l;
      float mq = aMQ[r]+bqm_l, aq = aAQ[r]+bqs_l;
      float e = eps[((size_t)t*4096 + (b0+g*4+r))*128 + col];
      float z = mq + __expf(0.5f*aq)*e;
      float d = mq - mp;
      kl[r] = 0.5f*(ap-aq) + 0.5f*(__expf(aq)+d*d)*__expf(-ap) - 0.5f;
      int li = ((col>>3)*16 + g*4 + r)*8 + (col&7);
      zbuf[li] = f2bf(z);
      if (t == nd4[r]-1) zidx[(size_t)(b0+g*4+r)*128 + col] = f2bf(z);
    }
    #pragma unroll
    for (int r=0;r<4;++r){
      kl[r] += __shfl_xor(kl[r], 1);
      kl[r] += __shfl_xor(kl[r], 2);
      kl[r] += __shfl_xor(kl[r], 4);
      kl[r] += __shfl_xor(kl[r], 8);
    }
    if (c==0){
      #pragma unroll
      for (int r=0;r<4;++r) klbuf[g*4+r][w] = kl[r];
    }
    __syncthreads();
    if (tid < 16){
      float s = 0.f;
      #pragma unroll
      for (int ww=0;ww<8;++ww) s += klbuf[tid][ww];
      out[(size_t)(b0+tid)*162 + 130 + t] = s;
    }
  }
}

// ---------------- head: g_T, y_T ----------------
__global__ __launch_bounds__(128) void head_k(
  const u16* __restrict__ hs, const u16* __restrict__ zidx,
  const int* __restrict__ n_days, const u16* __restrict__ Wgb,
  const float* __restrict__ bg, const float* __restrict__ Wy,
  const float* __restrict__ by, float* __restrict__ out)
{
  const int b = blockIdx.x;
  const int tid = threadIdx.x;
  __shared__ float hz[384];
  __shared__ float gl[128];
  const int idx = n_days[b]-1;
  const u16* hrow = hs + ((size_t)b*32 + idx)*256;
  for (int k=tid; k<256; k+=128) hz[k] = bf2f(hrow[k]);
  hz[256+tid] = bf2f(zidx[(size_t)b*128 + tid]);
  __syncthreads();
  const u16* wrow = Wgb + (size_t)tid*384;
  float s = 0.f;
  #pragma unroll 4
  for (int k8=0;k8<48;++k8){
    bf16x8 wv = *(const bf16x8*)&wrow[k8*8];
    #pragma unroll
    for (int e=0;e<8;++e) s += bf2f((u16)wv[e]) * hz[k8*8+e];
  }
  float gv = tanh_s(s + bg[tid]);
  out[(size_t)b*162 + tid] = gv;
  gl[tid] = gv;
  __syncthreads();
  if (tid == 0){
    float l0 = by[0], l1 = by[1];
    for (int k=0;k<128;++k){ l0 += gl[k]*Wy[k]; l1 += gl[k]*Wy[128+k]; }
    float mx = fmaxf(l0,l1);
    float e0 = __expf(l0-mx), e1 = __expf(l1-mx);
    float si = e0+e1;
    out[(size_t)b*162 + 128] = e0/si;
    out[(size_t)b*162 + 129] = e1/si;
  }
}

extern "C" void kernel_launch(void* const* d_in, const int* in_sizes, int n_in,
                              void* d_out, int out_size, void* d_ws, size_t ws_size,
                              hipStream_t stream)
{
  const float* x      = (const float*)d_in[0];
  const float* y_true = (const float*)d_in[1];
  const int*   n_days = (const int*)d_in[2];
  const float* z0     = (const float*)d_in[3];
  const float* eps    = (const float*)d_in[4];
  const float* W_ih   = (const float*)d_in[5];
  const float* W_hh   = (const float*)d_in[6];
  const float* b_ih   = (const float*)d_in[7];
  const float* b_hh   = (const float*)d_in[8];
  const float* Wph    = (const float*)d_in[9];
  const float* bph    = (const float*)d_in[10];
  const float* Woh    = (const float*)d_in[11];
  const float* boh    = (const float*)d_in[12];
  const float* Wpm    = (const float*)d_in[13];
  const float* bpm    = (const float*)d_in[14];
  const float* Wps    = (const float*)d_in[15];
  const float* bps    = (const float*)d_in[16];
  const float* Wqm    = (const float*)d_in[17];
  const float* bqm    = (const float*)d_in[18];
  const float* Wqs    = (const float*)d_in[19];
  const float* bqs    = (const float*)d_in[20];
  const float* Wg     = (const float*)d_in[21];
  const float* bg     = (const float*)d_in[22];
  const float* Wy     = (const float*)d_in[23];
  const float* by     = (const float*)d_in[24];
  (void)in_sizes; (void)n_in; (void)out_size; (void)ws_size;

  u16*   wsb = (u16*)d_ws;
  float* wsf = (float*)d_ws;
  u16* Wih_b = wsb + 0;
  u16* Whh_b = wsb + 196608;
  u16* Wc_b  = wsb + 393216;
  u16* Wz_b  = wsb + 524288;      // Wpz,Woz,Wpm,Wps,Wqm,Wqs consecutive (6 x 16384)
  u16* Wg_b  = wsb + 622592;
  float* Woy = wsf + 335872;
  float* bpq = wsf + 336128;
  u16* xbf   = wsb + 672768;
  u16* GI    = wsb + 34227200;
  u16* hsB   = wsb + 134890496;
  u16* HPQ   = wsb + 168444928;
  u16* zidx  = wsb + 201999360;   // end: 202523648 u16 = ~405 MB of ws

  hipLaunchKernelGGL(prep_w, dim3(2626), dim3(256), 0, stream,
                     W_ih, W_hh, Wph, Woh, Wpm, Wps, Wqm, Wqs, Wg, bph, boh,
                     wsb, Woy, bpq);
  hipLaunchKernelGGL(prep_x, dim3(16384), dim3(256), 0, stream, x, xbf);
  hipLaunchKernelGGL(gemm_bt, dim3(1024,3), dim3(512), 0, stream,
                     xbf, xbf, 256, 256, Wih_b, b_ih, GI, 768, 0,
                     (const float*)nullptr, (const float*)nullptr);
  hipLaunchKernelGGL(gru_seq, dim3(128), dim3(512), 0, stream,
                     GI, Whh_b, b_hh, n_days, hsB);
  hipLaunchKernelGGL(gemm_bt, dim3(1024,1), dim3(512), 0, stream,
                     xbf, hsB, 256, 512, Wc_b, bpq, HPQ, 256, 1, y_true, Woy);
  hipLaunchKernelGGL(vae_seq, dim3(256), dim3(512), 0, stream,
                     HPQ, z0, eps, n_days, Wz_b, bpm, bps, bqm, bqs, zidx, (float*)d_out);
  hipLaunchKernelGGL(head_k, dim3(4096), dim3(128), 0, stream,
                     hsB, zidx, n_days, Wg_b, bg, Wy, by, (float*)d_out);
}

// Round 2
// 602.138 us; speedup vs baseline: 1.9117x; 1.9117x over previous
//
#include <hip/hip_runtime.h>

typedef unsigned short u16;
typedef short bf16x8 __attribute__((ext_vector_type(8)));
typedef float f32x4 __attribute__((ext_vector_type(4)));

__device__ __forceinline__ float bf2f(u16 v){
  union { unsigned u; float f; } x; x.u = ((unsigned)v) << 16; return x.f;
}
__device__ __forceinline__ u16 f2bf(float f){
  union { float f; unsigned u; } x; x.f = f;
  unsigned u = x.u;
  u += 0x7fffu + ((u >> 16) & 1u);
  return (u16)(u >> 16);
}
__device__ __forceinline__ float sigm(float x){ return 1.f/(1.f+__expf(-x)); }
__device__ __forceinline__ float tanh_s(float x){ return 1.f - 2.f/(__expf(2.f*x)+1.f); }
__device__ __forceinline__ f32x4 mfma16(bf16x8 a, bf16x8 b, f32x4 c){
  return __builtin_amdgcn_mfma_f32_16x16x32_bf16(a, b, c, 0, 0, 0);
}
__device__ __forceinline__ void gl2lds16(const void* g, void* l){
  __builtin_amdgcn_global_load_lds(
      (const __attribute__((address_space(1))) unsigned int*)g,
      (__attribute__((address_space(3))) unsigned int*)l, 16, 0, 0);
}

// ---------------- prep: weights -> bf16 (+ layout splits) ----------------
__global__ void prep_w(const float* __restrict__ W_ih, const float* __restrict__ W_hh,
                       const float* __restrict__ Wph, const float* __restrict__ Woh,
                       const float* __restrict__ Wpm, const float* __restrict__ Wps,
                       const float* __restrict__ Wqm, const float* __restrict__ Wqs,
                       const float* __restrict__ Wg,  const float* __restrict__ bph,
                       const float* __restrict__ boh,
                       u16* __restrict__ wsb, float* __restrict__ Woy, float* __restrict__ bpq)
{
  int idx = blockIdx.x*256 + threadIdx.x;
  if (idx < 196608){ wsb[idx] = f2bf(W_ih[idx]); return; }
  if (idx < 393216){ wsb[idx] = f2bf(W_hh[idx-196608]); return; }
  if (idx < 524288){ int j = idx-393216; int row = j>>9, col = j&511;
    float v = (row<128) ? Wph[row*640+col] : Woh[(row-128)*642+col];
    wsb[idx] = f2bf(v); return; }
  if (idx < 540672){ int j = idx-524288; int row=j>>7, col=j&127; wsb[idx]=f2bf(Wph[row*640+512+col]); return; }
  if (idx < 557056){ int j = idx-540672; int row=j>>7, col=j&127; wsb[idx]=f2bf(Woh[row*642+514+col]); return; }
  if (idx < 573440){ wsb[idx]=f2bf(Wpm[idx-557056]); return; }
  if (idx < 589824){ wsb[idx]=f2bf(Wps[idx-573440]); return; }
  if (idx < 606208){ wsb[idx]=f2bf(Wqm[idx-589824]); return; }
  if (idx < 622592){ wsb[idx]=f2bf(Wqs[idx-606208]); return; }
  if (idx < 671744){ wsb[idx]=f2bf(Wg[idx-622592]); return; }
  if (idx < 672000){ int j = idx-671744; int row=j>>1; Woy[j] = Woh[row*642+512+(j&1)]; return; }
  if (idx < 672256){ int j = idx-672000; bpq[j] = (j<128) ? bph[j] : boh[j-128]; return; }
}

__global__ void prep_b(const float* __restrict__ b_ih, const float* __restrict__ b_hh,
                       float* __restrict__ bsum)
{
  int j = threadIdx.x;
  if (j < 768) bsum[j] = b_ih[j] + (j < 512 ? b_hh[j] : 0.f);
}

__global__ void prep_x(const float* __restrict__ x, u16* __restrict__ xbf){
  int i = blockIdx.x*256 + threadIdx.x;
  if (i >= 4194304) return;
  const float4* src = (const float4*)(x + (size_t)i*8);
  float4 a = src[0], b = src[1];
  uint4 o;
  o.x = (unsigned)f2bf(a.x) | ((unsigned)f2bf(a.y)<<16);
  o.y = (unsigned)f2bf(a.z) | ((unsigned)f2bf(a.w)<<16);
  o.z = (unsigned)f2bf(b.x) | ((unsigned)f2bf(b.y)<<16);
  o.w = (unsigned)f2bf(b.z) | ((unsigned)f2bf(b.w)<<16);
  ((uint4*)xbf)[i] = o;
}

// ---------------- generic C = A@W^T + bias (A may be [A1|A2] along K) ----------------
// grid (M/128, N/256), block 512.  C bf16; tmaj=1 -> row' = (m&31)*4096 + (m>>5).
__global__ __launch_bounds__(512, 4) void gemm_bt(
  const u16* __restrict__ A1, const u16* __restrict__ A2, int K1, int Ktot,
  const u16* __restrict__ W, const float* __restrict__ bias,
  u16* __restrict__ C, int N, int mode, int tmaj,
  const float* __restrict__ yt, const float* __restrict__ Woy)
{
  const int m0 = blockIdx.x*128;
  const int n0 = blockIdx.y*256;
  const int tid = threadIdx.x;
  const int w = tid>>6, lane = tid&63, c = lane&15, g = lane>>4;
  const int wm = w>>2, wn = w&3;
  const int K2 = Ktot - K1;
  __shared__ __align__(16) u16 abuf[8*128*8];   // [k8][row][8]
  __shared__ __align__(16) u16 wbuf[8*256*8];   // [k8][row][8]
  f32x4 acc[4][4];
  #pragma unroll
  for (int i=0;i<4;++i)
    #pragma unroll
    for (int j=0;j<4;++j) acc[i][j] = (f32x4){0.f,0.f,0.f,0.f};
  const int nch = Ktot >> 6;
  for (int kc=0; kc<nch; ++kc){
    __syncthreads();
    #pragma unroll
    for (int i=0;i<2;++i){
      int ii = w*2 + i;
      int p = ii*64 + lane;
      int k8 = p>>7, row = p&127;
      int k = (kc<<6) + k8*8;
      const u16* src = (k < K1) ? (A1 + (size_t)(m0+row)*K1 + k)
                                : (A2 + (size_t)(m0+row)*K2 + (k-K1));
      gl2lds16(src, &abuf[ii*512]);
    }
    #pragma unroll
    for (int i=0;i<4;++i){
      int ii = w*4 + i;
      int p = ii*64 + lane;
      int k8 = p>>8, row = p&255;
      int k = (kc<<6) + k8*8;
      const u16* src = W + (size_t)(n0+row)*Ktot + k;
      gl2lds16(src, &wbuf[ii*512]);
    }
    __syncthreads();
    #pragma unroll
    for (int ks=0;ks<2;++ks){
      int k8 = ks*4 + g;
      bf16x8 a[4];
      #pragma unroll
      for (int mt=0;mt<4;++mt) a[mt] = *(const bf16x8*)&abuf[(k8*128 + wm*64 + mt*16 + c)*8];
      #pragma unroll
      for (int nt=0;nt<4;++nt){
        bf16x8 b = *(const bf16x8*)&wbuf[(k8*256 + wn*64 + nt*16 + c)*8];
        #pragma unroll
        for (int mt=0;mt<4;++mt)
          acc[mt][nt] = mfma16(a[mt], b, acc[mt][nt]);
      }
    }
  }
  #pragma unroll
  for (int nt=0;nt<4;++nt){
    int n = n0 + wn*64 + nt*16 + c;
    float bn = bias[n];
    float wy0 = 0.f, wy1 = 0.f;
    bool yfl = (mode==1) && (n >= 128);
    if (yfl){ wy0 = Woy[(n-128)*2]; wy1 = Woy[(n-128)*2+1]; }
    #pragma unroll
    for (int mt=0;mt<4;++mt){
      #pragma unroll
      for (int r=0;r<4;++r){
        size_t m = (size_t)m0 + wm*64 + mt*16 + g*4 + r;
        float v = acc[mt][nt][r] + bn;
        if (yfl) v += yt[2*m]*wy0 + yt[2*m+1]*wy1;
        size_t row = tmaj ? (size_t)(m&31)*4096 + (m>>5) : m;
        C[row*(size_t)N + n] = f2bf(v);
      }
    }
  }
}

// ---------------- sequential GRU over T; W_hh register-resident ----------------
// 256 blocks x 1024 threads, 16 batch rows/block. GI t-major [t][4096][768].
__global__ __launch_bounds__(1024, 4) void gru_seq(
  const u16* __restrict__ GI, const u16* __restrict__ Whh,
  const float* __restrict__ bhh, const int* __restrict__ n_days,
  u16* __restrict__ hs)
{
  const int b0 = blockIdx.x*16;
  const int tid = threadIdx.x;
  const int w = tid>>6, lane = tid&63, c = lane&15, g = lane>>4;
  const int j0 = w*16 + g*4;                 // this thread's 4 h-cols (batch = c)
  __shared__ __align__(16) u16 hbuf[32*16*8];      // [k8 32][batch 16][8] = 8KB
  __shared__ __align__(16) u16 gibuf[3*16*768];    // 3 x 24KB, row-swizzled fill

  // W_hh fragments, register resident: first-operand rows = W rows (gate-aligned)
  bf16x8 wa[3][8];
  #pragma unroll
  for (int gate=0; gate<3; ++gate)
    #pragma unroll
    for (int ks=0; ks<8; ++ks)
      wa[gate][ks] = *(const bf16x8*)&Whh[(size_t)(gate*256 + w*16 + c)*256 + ks*32 + g*8];

  const float4 bhn4 = *(const float4*)(bhh + 512 + j0);
  const int ndc = n_days[b0 + c];

  // prefetch source offsets (elements), row-swizzled
  int so0, so1;
  { int pe = w*512 + lane*8; int row = pe/768, off = pe%768;
    so0 = (b0+row)*768 + (off ^ ((row&7)<<3)); }
  { int pe = (16+w)*512 + lane*8; int row = pe/768, off = pe%768;
    so1 = (b0+row)*768 + (off ^ ((row&7)<<3)); }
  const int rd0 = c*1536 + ((w*32 + g*8) ^ ((c&7)<<4));   // gibuf read (bytes)
  const int hroff = (g*16 + c)*16;                         // hbuf frag read base
  const int hwoff = ((w*2 + (g>>1))*16 + c)*16 + (g&1)*8;  // hbuf write (bytes)
  u16* hsp = hs + ((size_t)(b0+c)*32)*256 + j0;

  float hprev[4] = {0.f,0.f,0.f,0.f};
  for (int i=tid; i<512; i+=1024) ((uint4*)hbuf)[i] = make_uint4(0,0,0,0);

  // prologue: planes 0,1
  {
    const u16* gp0 = GI;
    const u16* gp1 = GI + 3145728;
    gl2lds16(gp0 + so0, (char*)gibuf + 0*24576 + w*1024);
    if (w < 8) gl2lds16(gp0 + so1, (char*)gibuf + 0*24576 + (16+w)*1024);
    gl2lds16(gp1 + so0, (char*)gibuf + 1*24576 + w*1024);
    if (w < 8) gl2lds16(gp1 + so1, (char*)gibuf + 1*24576 + (16+w)*1024);
  }
  __syncthreads();   // drains prologue loads; hbuf zeros visible

  int cur = 0;
  #pragma unroll 1
  for (int t=0; t<32; ++t){
    // Phase A: prefetch plane t+2 into buffer (cur+2)%3
    {
      int nxt = cur >= 1 ? cur-1 : cur+2;
      int plane = (t+2 < 32) ? t+2 : 31;
      const u16* gp = GI + (size_t)plane*3145728;
      gl2lds16(gp + so0, (char*)gibuf + nxt*24576 + w*1024);
      if (w < 8) gl2lds16(gp + so1, (char*)gibuf + nxt*24576 + (16+w)*1024);
    }
    // Phase B: MFMA  (gh^T: D[Wrow][batch])
    f32x4 aR = (f32x4){0.f,0.f,0.f,0.f};
    f32x4 aU = (f32x4){0.f,0.f,0.f,0.f};
    f32x4 aN = (f32x4){bhn4.x, bhn4.y, bhn4.z, bhn4.w};
    #pragma unroll
    for (int ks=0; ks<8; ++ks){
      bf16x8 hf = *(const bf16x8*)((const char*)hbuf + hroff + ks*1024);
      aR = mfma16(wa[0][ks], hf, aR);
      aU = mfma16(wa[1][ks], hf, aU);
      aN = mfma16(wa[2][ks], hf, aN);
    }
    // Phase C: wait GI plane t, gates
    if (w < 8) asm volatile("s_waitcnt vmcnt(4)" ::: "memory");
    else       asm volatile("s_waitcnt vmcnt(2)" ::: "memory");
    __builtin_amdgcn_sched_barrier(0);
    __builtin_amdgcn_s_barrier();
    __builtin_amdgcn_sched_barrier(0);
    {
      const char* gib = (const char*)gibuf + cur*24576;
      ushort4 gr_ = *(const ushort4*)(gib + rd0);
      ushort4 gu_ = *(const ushort4*)(gib + rd0 + 512);
      ushort4 gn_ = *(const ushort4*)(gib + rd0 + 1024);
      u16 hb[4];
      #pragma unroll
      for (int r=0; r<4; ++r){
        u16 grv = r==0?gr_.x : r==1?gr_.y : r==2?gr_.z : gr_.w;
        u16 guv = r==0?gu_.x : r==1?gu_.y : r==2?gu_.z : gu_.w;
        u16 gnv = r==0?gn_.x : r==1?gn_.y : r==2?gn_.z : gn_.w;
        float rr = sigm(bf2f(grv) + aR[r]);
        float uu = sigm(bf2f(guv) + aU[r]);
        float nn = tanh_s(bf2f(gnv) + rr*aN[r]);
        float h = (1.f-uu)*nn + uu*hprev[r];
        hprev[r] = h;
        hb[r] = f2bf(h);
      }
      uint2 hpk;
      hpk.x = (unsigned)hb[0] | ((unsigned)hb[1]<<16);
      hpk.y = (unsigned)hb[2] | ((unsigned)hb[3]<<16);
      *(uint2*)((char*)hbuf + hwoff) = hpk;
      uint2 hst = (t < ndc) ? hpk : make_uint2(0u,0u);
      *(uint2*)(hsp + t*256) = hst;
    }
    // Phase D: publish hbuf
    asm volatile("s_waitcnt lgkmcnt(0)" ::: "memory");
    __builtin_amdgcn_sched_barrier(0);
    __builtin_amdgcn_s_barrier();
    __builtin_amdgcn_sched_barrier(0);
    cur = cur==2 ? 0 : cur+1;
  }
}

// ---------------- sequential VAE scan; swapped operands, staged HPQ/eps ----------------
// 256 blocks x 512 threads, 16 batch rows/block. HPQ t-major [t][4096][256].
__global__ __launch_bounds__(512, 2) void vae_seq(
  const u16* __restrict__ HPQ, const float* __restrict__ z0,
  const float* __restrict__ eps, const int* __restrict__ n_days,
  const u16* __restrict__ Wm,
  const float* __restrict__ bpm, const float* __restrict__ bps,
  const float* __restrict__ bqm, const float* __restrict__ bqs,
  u16* __restrict__ zidx, float* __restrict__ out)
{
  const int b0 = blockIdx.x*16;
  const int tid = threadIdx.x, w = tid>>6, lane = tid&63, c = lane&15, g = lane>>4;
  const int j0 = w*16 + g*4;                 // this thread's 4 z-dims (batch = c)
  __shared__ __align__(16) u16 zbuf[16*16*8];      // [k8 16][batch 16][8] 4KB
  __shared__ __align__(16) u16 hzpb[16*16*8];
  __shared__ __align__(16) u16 hzqb[16*16*8];
  __shared__ __align__(16) char hpql[3*8192];      // swizzled [batch 16][512B]
  __shared__ __align__(16) char epsl[3*8192];      // swizzled [batch 16][512B]
  __shared__ float klbuf[16][8];

  bf16x8 wf[6][4];
  #pragma unroll
  for (int mat=0;mat<6;++mat)
    #pragma unroll
    for (int ks=0;ks<4;++ks)
      wf[mat][ks] = *(const bf16x8*)&Wm[mat*16384 + (w*16+c)*128 + ks*32 + g*8];

  const float4 bpm4 = *(const float4*)(bpm + j0);
  const float4 bps4 = *(const float4*)(bps + j0);
  const float4 bqm4 = *(const float4*)(bqm + j0);
  const float4 bqs4 = *(const float4*)(bqs + j0);
  const int ndc = n_days[b0 + c];

  int soH, soE;
  { int p = (w*64 + lane)*16; int row = p/512, off = p%512;
    int so = off ^ ((row&7)<<4);
    soH = (b0+row)*256 + (so>>1);
    soE = (b0+row)*128 + (so>>2); }
  const int rdH = c*512 + ((j0*2) ^ ((c&7)<<4));
  const int rdE = c*512 + ((j0*4) ^ ((c&7)<<4));
  const int hroff = (g*16 + c)*16;
  const int hwoff = ((w*2 + (g>>1))*16 + c)*16 + (g&1)*8;

  if (tid < 256){
    int k8 = tid>>4, row = tid&15;
    const float* zp = z0 + (size_t)(b0+row)*128 + k8*8;
    uint4 o;
    o.x = (unsigned)f2bf(zp[0]) | ((unsigned)f2bf(zp[1])<<16);
    o.y = (unsigned)f2bf(zp[2]) | ((unsigned)f2bf(zp[3])<<16);
    o.z = (unsigned)f2bf(zp[4]) | ((unsigned)f2bf(zp[5])<<16);
    o.w = (unsigned)f2bf(zp[6]) | ((unsigned)f2bf(zp[7])<<16);
    ((uint4*)zbuf)[tid] = o;
  }
  // prologue prefetch planes 0,1
  gl2lds16(HPQ + 0*1048576 + soH, hpql + 0*8192 + w*1024);
  gl2lds16(eps + 0*524288  + soE, epsl + 0*8192 + w*1024);
  gl2lds16(HPQ + 1*1048576 + soH, hpql + 1*8192 + w*1024);
  gl2lds16(eps + 1*524288  + soE, epsl + 1*8192 + w*1024);
  __syncthreads();

  int cur = 0;
  #pragma unroll 1
  for (int t=0; t<32; ++t){
    // A: prefetch t+2
    {
      int nxt = cur >= 1 ? cur-1 : cur+2;
      int plane = (t+2 < 32) ? t+2 : 31;
      gl2lds16(HPQ + (size_t)plane*1048576 + soH, hpql + nxt*8192 + w*1024);
      gl2lds16(eps + (size_t)plane*524288  + soE, epsl + nxt*8192 + w*1024);
    }
    // B: stage-1 MFMA (z-part of prior/posterior hidden)
    f32x4 accP = (f32x4){0,0,0,0}, accQ = (f32x4){0,0,0,0};
    #pragma unroll
    for (int ks=0;ks<4;++ks){
      bf16x8 zf = *(const bf16x8*)((const char*)zbuf + hroff + ks*1024);
      accP = mfma16(wf[0][ks], zf, accP);
      accQ = mfma16(wf[1][ks], zf, accQ);
    }
    // C: combine with staged HPQ, tanh, stage to LDS
    asm volatile("s_waitcnt vmcnt(4)" ::: "memory");
    __builtin_amdgcn_sched_barrier(0);
    __builtin_amdgcn_s_barrier();
    __builtin_amdgcn_sched_barrier(0);
    {
      const char* hb_ = hpql + cur*8192;
      ushort4 hp4 = *(const ushort4*)(hb_ + rdH);
      ushort4 hq4 = *(const ushort4*)(hb_ + rdH + 256);
      u16 pb[4], qb[4];
      #pragma unroll
      for (int r=0;r<4;++r){
        u16 pv = r==0?hp4.x : r==1?hp4.y : r==2?hp4.z : hp4.w;
        u16 qv = r==0?hq4.x : r==1?hq4.y : r==2?hq4.z : hq4.w;
        pb[r] = f2bf(tanh_s(bf2f(pv) + accP[r]));
        qb[r] = f2bf(tanh_s(bf2f(qv) + accQ[r]));
      }
      uint2 ppk, qpk;
      ppk.x = (unsigned)pb[0] | ((unsigned)pb[1]<<16);
      ppk.y = (unsigned)pb[2] | ((unsigned)pb[3]<<16);
      qpk.x = (unsigned)qb[0] | ((unsigned)qb[1]<<16);
      qpk.y = (unsigned)qb[2] | ((unsigned)qb[3]<<16);
      *(uint2*)((char*)hzpb + hwoff) = ppk;
      *(uint2*)((char*)hzqb + hwoff) = qpk;
    }
    asm volatile("s_waitcnt lgkmcnt(0)" ::: "memory");
    __builtin_amdgcn_sched_barrier(0);
    __builtin_amdgcn_s_barrier();
    __builtin_amdgcn_sched_barrier(0);
    // D: stage-2 MFMAs + KL + z
    {
      f32x4 aMP=(f32x4){0,0,0,0}, aAP=(f32x4){0,0,0,0};
      f32x4 aMQ=(f32x4){0,0,0,0}, aAQ=(f32x4){0,0,0,0};
      #pragma unroll
      for (int ks=0;ks<4;++ks){
        bf16x8 pf = *(const bf16x8*)((const char*)hzpb + hroff + ks*1024);
        bf16x8 qf = *(const bf16x8*)((const char*)hzqb + hroff + ks*1024);
        aMP = mfma16(wf[2][ks], pf, aMP);
        aAP = mfma16(wf[3][ks], pf, aAP);
        aMQ = mfma16(wf[4][ks], qf, aMQ);
        aAQ = mfma16(wf[5][ks], qf, aAQ);
      }
      float4 e4 = *(const float4*)(epsl + cur*8192 + rdE);
      float kls = 0.f;
      u16 zb4[4];
      #pragma unroll
      for (int r=0;r<4;++r){
        float mp = aMP[r]+(r==0?bpm4.x:r==1?bpm4.y:r==2?bpm4.z:bpm4.w);
        float ap = aAP[r]+(r==0?bps4.x:r==1?bps4.y:r==2?bps4.z:bps4.w);
        float mq = aMQ[r]+(r==0?bqm4.x:r==1?bqm4.y:r==2?bqm4.z:bqm4.w);
        float aq = aAQ[r]+(r==0?bqs4.x:r==1?bqs4.y:r==2?bqs4.z:bqs4.w);
        float ev = r==0?e4.x : r==1?e4.y : r==2?e4.z : e4.w;
        float z = mq + __expf(0.5f*aq)*ev;
        float d = mq - mp;
        kls += 0.5f*(ap-aq) + 0.5f*(__expf(aq)+d*d)*__expf(-ap) - 0.5f;
        zb4[r] = f2bf(z);
      }
      uint2 zpk;
      zpk.x = (unsigned)zb4[0] | ((unsigned)zb4[1]<<16);
      zpk.y = (unsigned)zb4[2] | ((unsigned)zb4[3]<<16);
      *(uint2*)((char*)zbuf + hwoff) = zpk;
      if (t == ndc-1) *(uint2*)(zidx + (size_t)(b0+c)*128 + j0) = zpk;
      kls += __shfl_xor(kls, 16);
      kls += __shfl_xor(kls, 32);
      if (lane < 16) klbuf[c][w] = kls;
    }
    asm volatile("s_waitcnt lgkmcnt(0)" ::: "memory");
    __builtin_amdgcn_sched_barrier(0);
    __builtin_amdgcn_s_barrier();
    __builtin_amdgcn_sched_barrier(0);
    if (tid < 16){
      float s = 0.f;
      #pragma unroll
      for (int ww=0;ww<8;++ww) s += klbuf[tid][ww];
      out[(size_t)(b0+tid)*162 + 130 + t] = s;
    }
    cur = cur==2 ? 0 : cur+1;
  }
}

// ---------------- head: g_T, y_T ----------------
__global__ __launch_bounds__(128) void head_k(
  const u16* __restrict__ hs, const u16* __restrict__ zidx,
  const int* __restrict__ n_days, const u16* __restrict__ Wgb,
  const float* __restrict__ bg, const float* __restrict__ Wy,
  const float* __restrict__ by, float* __restrict__ out)
{
  const int b = blockIdx.x;
  const int tid = threadIdx.x;
  const int lane = tid & 63, wv = tid >> 6;
  __shared__ float hz[384];
  __shared__ float red[2][2];
  const int idx = n_days[b]-1;
  const u16* hrow = hs + ((size_t)b*32 + idx)*256;
  for (int k=tid; k<256; k+=128) hz[k] = bf2f(hrow[k]);
  hz[256+tid] = bf2f(zidx[(size_t)b*128 + tid]);
  __syncthreads();
  const u16* wrow = Wgb + (size_t)tid*384;
  float s = 0.f;
  #pragma unroll 4
  for (int k8=0;k8<48;++k8){
    bf16x8 wvv = *(const bf16x8*)&wrow[k8*8];
    #pragma unroll
    for (int e=0;e<8;++e) s += bf2f((u16)wvv[e]) * hz[k8*8+e];
  }
  float gv = tanh_s(s + bg[tid]);
  out[(size_t)b*162 + tid] = gv;
  float a0 = gv*Wy[tid], a1 = gv*Wy[128+tid];
  #pragma unroll
  for (int off=1; off<64; off<<=1){
    a0 += __shfl_xor(a0, off);
    a1 += __shfl_xor(a1, off);
  }
  if (lane == 0){ red[0][wv] = a0; red[1][wv] = a1; }
  __syncthreads();
  if (tid == 0){
    float l0 = by[0] + red[0][0] + red[0][1];
    float l1 = by[1] + red[1][0] + red[1][1];
    float mx = fmaxf(l0,l1);
    float e0 = __expf(l0-mx), e1 = __expf(l1-mx);
    float si = e0+e1;
    out[(size_t)b*162 + 128] = e0/si;
    out[(size_t)b*162 + 129] = e1/si;
  }
}

extern "C" void kernel_launch(void* const* d_in, const int* in_sizes, int n_in,
                              void* d_out, int out_size, void* d_ws, size_t ws_size,
                              hipStream_t stream)
{
  const float* x      = (const float*)d_in[0];
  const float* y_true = (const float*)d_in[1];
  const int*   n_days = (const int*)d_in[2];
  const float* z0     = (const float*)d_in[3];
  const float* eps    = (const float*)d_in[4];
  const float* W_ih   = (const float*)d_in[5];
  const float* W_hh   = (const float*)d_in[6];
  const float* b_ih   = (const float*)d_in[7];
  const float* b_hh   = (const float*)d_in[8];
  const float* Wph    = (const float*)d_in[9];
  const float* bph    = (const float*)d_in[10];
  const float* Woh    = (const float*)d_in[11];
  const float* boh    = (const float*)d_in[12];
  const float* Wpm    = (const float*)d_in[13];
  const float* bpm    = (const float*)d_in[14];
  const float* Wps    = (const float*)d_in[15];
  const float* bps    = (const float*)d_in[16];
  const float* Wqm    = (const float*)d_in[17];
  const float* bqm    = (const float*)d_in[18];
  const float* Wqs    = (const float*)d_in[19];
  const float* bqs    = (const float*)d_in[20];
  const float* Wg     = (const float*)d_in[21];
  const float* bg     = (const float*)d_in[22];
  const float* Wy     = (const float*)d_in[23];
  const float* by     = (const float*)d_in[24];
  (void)in_sizes; (void)n_in; (void)out_size; (void)ws_size;

  u16*   wsb = (u16*)d_ws;
  float* wsf = (float*)d_ws;
  u16* Wih_b = wsb + 0;
  u16* Whh_b = wsb + 196608;
  u16* Wc_b  = wsb + 393216;
  u16* Wz_b  = wsb + 524288;      // 6 x 128x128 mats consecutive
  u16* Wg_b  = wsb + 622592;
  float* Woy  = wsf + 335872;
  float* bpq  = wsf + 336128;
  float* bsum = wsf + 336384;
  u16* xbf   = wsb + 674304;
  u16* GI    = wsb + 34228736;    // t-major [32][4096][768]
  u16* hsB   = wsb + 134892032;   // [b][t][256]
  u16* HPQ   = wsb + 168446464;   // t-major [32][4096][256]
  u16* zidx  = wsb + 202000896;   // [b][128]; end ~405MB

  hipLaunchKernelGGL(prep_w, dim3(2626), dim3(256), 0, stream,
                     W_ih, W_hh, Wph, Woh, Wpm, Wps, Wqm, Wqs, Wg, bph, boh,
                     wsb, Woy, bpq);
  hipLaunchKernelGGL(prep_b, dim3(1), dim3(768), 0, stream, b_ih, b_hh, bsum);
  hipLaunchKernelGGL(prep_x, dim3(16384), dim3(256), 0, stream, x, xbf);
  hipLaunchKernelGGL(gemm_bt, dim3(1024,3), dim3(512), 0, stream,
                     xbf, xbf, 256, 256, Wih_b, bsum, GI, 768, 0, 1,
                     (const float*)nullptr, (const float*)nullptr);
  hipLaunchKernelGGL(gru_seq, dim3(256), dim3(1024), 0, stream,
                     GI, Whh_b, b_hh, n_days, hsB);
  hipLaunchKernelGGL(gemm_bt, dim3(1024,1), dim3(512), 0, stream,
                     xbf, hsB, 256, 512, Wc_b, bpq, HPQ, 256, 1, 1, y_true, Woy);
  hipLaunchKernelGGL(vae_seq, dim3(256), dim3(512), 0, stream,
                     HPQ, z0, eps, n_days, Wz_b, bpm, bps, bqm, bqs, zidx, (float*)d_out);
  hipLaunchKernelGGL(head_k, dim3(4096), dim3(128), 0, stream,
                     hsB, zidx, n_days, Wg_b, bg, Wy, by, (float*)d_out);
}

// Round 3
// 546.017 us; speedup vs baseline: 2.1082x; 1.1028x over previous
//
#include <hip/hip_runtime.h>

typedef unsigned short u16;
typedef short bf16x8 __attribute__((ext_vector_type(8)));
typedef float f32x4 __attribute__((ext_vector_type(4)));

__device__ __forceinline__ float bf2f(u16 v){
  union { unsigned u; float f; } x; x.u = ((unsigned)v) << 16; return x.f;
}
__device__ __forceinline__ u16 f2bf(float f){
  union { float f; unsigned u; } x; x.f = f;
  unsigned u = x.u;
  u += 0x7fffu + ((u >> 16) & 1u);
  return (u16)(u >> 16);
}
__device__ __forceinline__ unsigned pk_bf16(float lo, float hi){
  unsigned r;
  asm volatile("v_cvt_pk_bf16_f32 %0, %1, %2" : "=v"(r) : "v"(lo), "v"(hi));
  return r;
}
__device__ __forceinline__ float sigm(float x){ return 1.f/(1.f+__expf(-x)); }
__device__ __forceinline__ float tanh_s(float x){ return 1.f - 2.f/(__expf(2.f*x)+1.f); }
__device__ __forceinline__ f32x4 mfma16(bf16x8 a, bf16x8 b, f32x4 c){
  return __builtin_amdgcn_mfma_f32_16x16x32_bf16(a, b, c, 0, 0, 0);
}
__device__ __forceinline__ void gl2lds16(const void* g, void* l){
  __builtin_amdgcn_global_load_lds(
      (const __attribute__((address_space(1))) unsigned int*)g,
      (__attribute__((address_space(3))) unsigned int*)l, 16, 0, 0);
}

// ---------------- prep: weights -> bf16 (+ layout splits) ----------------
__global__ void prep_w(const float* __restrict__ W_ih, const float* __restrict__ W_hh,
                       const float* __restrict__ Wph, const float* __restrict__ Woh,
                       const float* __restrict__ Wpm, const float* __restrict__ Wps,
                       const float* __restrict__ Wqm, const float* __restrict__ Wqs,
                       const float* __restrict__ Wg,  const float* __restrict__ bph,
                       const float* __restrict__ boh,
                       u16* __restrict__ wsb, float* __restrict__ Woy, float* __restrict__ bpq)
{
  int idx = blockIdx.x*256 + threadIdx.x;
  if (idx < 196608){ wsb[idx] = f2bf(W_ih[idx]); return; }
  if (idx < 393216){ wsb[idx] = f2bf(W_hh[idx-196608]); return; }
  if (idx < 524288){ int j = idx-393216; int row = j>>9, col = j&511;
    float v = (row<128) ? Wph[row*640+col] : Woh[(row-128)*642+col];
    wsb[idx] = f2bf(v); return; }
  if (idx < 540672){ int j = idx-524288; int row=j>>7, col=j&127; wsb[idx]=f2bf(Wph[row*640+512+col]); return; }
  if (idx < 557056){ int j = idx-540672; int row=j>>7, col=j&127; wsb[idx]=f2bf(Woh[row*642+514+col]); return; }
  if (idx < 573440){ wsb[idx]=f2bf(Wpm[idx-557056]); return; }
  if (idx < 589824){ wsb[idx]=f2bf(Wps[idx-573440]); return; }
  if (idx < 606208){ wsb[idx]=f2bf(Wqm[idx-589824]); return; }
  if (idx < 622592){ wsb[idx]=f2bf(Wqs[idx-606208]); return; }
  if (idx < 671744){ wsb[idx]=f2bf(Wg[idx-622592]); return; }
  if (idx < 672000){ int j = idx-671744; int row=j>>1; Woy[j] = Woh[row*642+512+(j&1)]; return; }
  if (idx < 672256){ int j = idx-672000; bpq[j] = (j<128) ? bph[j] : boh[j-128]; return; }
}

__global__ void prep_b(const float* __restrict__ b_ih, const float* __restrict__ b_hh,
                       float* __restrict__ bsum)
{
  int j = threadIdx.x;
  if (j < 768) bsum[j] = b_ih[j] + (j < 512 ? b_hh[j] : 0.f);
}

__global__ void prep_x(const float* __restrict__ x, u16* __restrict__ xbf){
  int i = blockIdx.x*256 + threadIdx.x;
  if (i >= 4194304) return;
  const float4* src = (const float4*)(x + (size_t)i*8);
  float4 a = src[0], b = src[1];
  uint4 o;
  o.x = pk_bf16(a.x, a.y);
  o.y = pk_bf16(a.z, a.w);
  o.z = pk_bf16(b.x, b.y);
  o.w = pk_bf16(b.z, b.w);
  ((uint4*)xbf)[i] = o;
}

// ---------------- generic C = A@W^T + bias (A may be [A1|A2] along K) ----------------
// grid (M/128, N/256), block 512.  C bf16 m-major [M][N].
__global__ __launch_bounds__(512, 4) void gemm_bt(
  const u16* __restrict__ A1, const u16* __restrict__ A2, int K1, int Ktot,
  const u16* __restrict__ W, const float* __restrict__ bias,
  u16* __restrict__ C, int N, int mode,
  const float* __restrict__ yt, const float* __restrict__ Woy)
{
  const int m0 = blockIdx.x*128;
  const int n0 = blockIdx.y*256;
  const int tid = threadIdx.x;
  const int w = tid>>6, lane = tid&63, c = lane&15, g = lane>>4;
  const int wm = w>>2, wn = w&3;
  const int K2 = Ktot - K1;
  __shared__ __align__(16) u16 abuf[8*128*8];   // [k8][row][8]
  __shared__ __align__(16) u16 wbuf[8*256*8];   // [k8][row][8]
  f32x4 acc[4][4];
  #pragma unroll
  for (int i=0;i<4;++i)
    #pragma unroll
    for (int j=0;j<4;++j) acc[i][j] = (f32x4){0.f,0.f,0.f,0.f};
  const int nch = Ktot >> 6;
  for (int kc=0; kc<nch; ++kc){
    __syncthreads();
    #pragma unroll
    for (int i=0;i<2;++i){
      int ii = w*2 + i;
      int p = ii*64 + lane;
      int k8 = p>>7, row = p&127;
      int k = (kc<<6) + k8*8;
      const u16* src = (k < K1) ? (A1 + (size_t)(m0+row)*K1 + k)
                                : (A2 + (size_t)(m0+row)*K2 + (k-K1));
      gl2lds16(src, &abuf[ii*512]);
    }
    #pragma unroll
    for (int i=0;i<4;++i){
      int ii = w*4 + i;
      int p = ii*64 + lane;
      int k8 = p>>8, row = p&255;
      int k = (kc<<6) + k8*8;
      const u16* src = W + (size_t)(n0+row)*Ktot + k;
      gl2lds16(src, &wbuf[ii*512]);
    }
    __syncthreads();
    #pragma unroll
    for (int ks=0;ks<2;++ks){
      int k8 = ks*4 + g;
      bf16x8 a[4];
      #pragma unroll
      for (int mt=0;mt<4;++mt) a[mt] = *(const bf16x8*)&abuf[(k8*128 + wm*64 + mt*16 + c)*8];
      #pragma unroll
      for (int nt=0;nt<4;++nt){
        bf16x8 b = *(const bf16x8*)&wbuf[(k8*256 + wn*64 + nt*16 + c)*8];
        #pragma unroll
        for (int mt=0;mt<4;++mt)
          acc[mt][nt] = mfma16(a[mt], b, acc[mt][nt]);
      }
    }
  }
  #pragma unroll
  for (int nt=0;nt<4;++nt){
    int n = n0 + wn*64 + nt*16 + c;
    float bn = bias[n];
    float wy0 = 0.f, wy1 = 0.f;
    bool yfl = (mode==1) && (n >= 128);
    if (yfl){ wy0 = Woy[(n-128)*2]; wy1 = Woy[(n-128)*2+1]; }
    #pragma unroll
    for (int mt=0;mt<4;++mt){
      #pragma unroll
      for (int r=0;r<4;++r){
        size_t m = (size_t)m0 + wm*64 + mt*16 + g*4 + r;
        float v = acc[mt][nt][r] + bn;
        if (yfl) v += yt[2*m]*wy0 + yt[2*m+1]*wy1;
        C[m*(size_t)N + n] = f2bf(v);
      }
    }
  }
}

// ---------------- sequential GRU over T; W_hh register-resident ----------------
// 256 blocks x 1024 threads, 16 batch rows/block. GI m-major [B*T][768].
// Single barrier per timestep; hbuf double-buffered; counted vmcnt.
__global__ __launch_bounds__(1024) void gru_seq(
  const u16* __restrict__ GI, const u16* __restrict__ Whh,
  const float* __restrict__ bhh, const int* __restrict__ n_days,
  u16* __restrict__ hs)
{
  const int b0 = blockIdx.x*16;
  const int tid = threadIdx.x;
  const int w = tid>>6, lane = tid&63, c = lane&15, g = lane>>4;
  const int j0 = w*16 + g*4;                 // this thread's 4 h-cols (batch = c)
  __shared__ __align__(16) u16 hbuf[2][32*16*8];   // [buf][k8 32][batch 16][8] 8KB each
  __shared__ __align__(16) u16 gibuf[3][16*768];   // 3 x 24KB, row-swizzled fill
  __shared__ float bhnl[256];

  // W_hh fragments, register resident (96 VGPR)
  bf16x8 wa[3][8];
  #pragma unroll
  for (int gate=0; gate<3; ++gate)
    #pragma unroll
    for (int ks=0; ks<8; ++ks)
      wa[gate][ks] = *(const bf16x8*)&Whh[(size_t)(gate*256 + w*16 + c)*256 + ks*32 + g*8];

  if (tid < 256) bhnl[tid] = bhh[512 + tid];
  const int ndc = n_days[b0 + c];

  // prefetch source offsets (elements), m-major, row-swizzled 16B granules
  int so0, so1;
  { int pe = w*512 + lane*8; int row = pe/768, off = pe%768;
    so0 = (b0+row)*32*768 + (off ^ ((row&7)<<3)); }
  { int pe = (16+w)*512 + lane*8; int row = pe/768, off = pe%768;
    so1 = (b0+row)*32*768 + (off ^ ((row&7)<<3)); }
  const int rd0 = c*1536 + ((j0*2) ^ ((c&7)<<4));   // gibuf read (bytes)
  const int hroff = (g*16 + c)*16;                   // hbuf frag read base (bytes)
  const int hwoff = ((w*2 + (g>>1))*16 + c)*16 + (g&1)*8;  // hbuf write (bytes)
  u16* hsp = hs + ((size_t)(b0+c)*32)*256 + j0;

  float hprev[4] = {0.f,0.f,0.f,0.f};
  if (tid < 512) ((uint4*)hbuf[0])[tid] = make_uint4(0,0,0,0);

  // prologue: planes 0,1
  gl2lds16(GI + so0,       (char*)gibuf[0] + w*1024);
  if (w < 8) gl2lds16(GI + so1, (char*)gibuf[0] + (16+w)*1024);
  gl2lds16(GI + so0 + 768, (char*)gibuf[1] + w*1024);
  if (w < 8) gl2lds16(GI + so1 + 768, (char*)gibuf[1] + (16+w)*1024);
  asm volatile("s_waitcnt vmcnt(0)" ::: "memory");
  __syncthreads();

  const u16* hr = hbuf[0];
  u16*       hw = hbuf[1];
  int cur = 0;
  #pragma unroll 1
  for (int t=0; t<32; ++t){
    // A: prefetch plane t+2
    if (t < 30){
      int nxt3 = cur >= 1 ? cur-1 : 2;
      const u16* gp = GI + (t+2)*768;
      gl2lds16(gp + so0, (char*)gibuf[nxt3] + w*1024);
      if (w < 8) gl2lds16(gp + so1, (char*)gibuf[nxt3] + (16+w)*1024);
    }
    // W1: ensure plane t+1 resident (counts include hs store of t-1)
    if (t < 30){
      if (w < 8) asm volatile("s_waitcnt vmcnt(3)" ::: "memory");
      else       asm volatile("s_waitcnt vmcnt(2)" ::: "memory");
    } else if (t == 30){
      asm volatile("s_waitcnt vmcnt(1)" ::: "memory");
    }
    __builtin_amdgcn_sched_barrier(0);
    // B: MFMA  (gh^T: D[Wrow][batch])
    f32x4 aR = (f32x4){0.f,0.f,0.f,0.f};
    f32x4 aU = (f32x4){0.f,0.f,0.f,0.f};
    float4 bhn4 = *(const float4*)&bhnl[j0];
    f32x4 aN = (f32x4){bhn4.x, bhn4.y, bhn4.z, bhn4.w};
    #pragma unroll
    for (int ks=0; ks<8; ++ks){
      bf16x8 hf = *(const bf16x8*)((const char*)hr + hroff + ks*1024);
      aR = mfma16(wa[0][ks], hf, aR);
      aU = mfma16(wa[1][ks], hf, aU);
      aN = mfma16(wa[2][ks], hf, aN);
    }
    // C: gates from gibuf plane t
    {
      const char* gib = (const char*)gibuf[cur];
      ushort4 gr_ = *(const ushort4*)(gib + rd0);
      ushort4 gu_ = *(const ushort4*)(gib + rd0 + 512);
      ushort4 gn_ = *(const ushort4*)(gib + rd0 + 1024);
      float h4[4];
      #pragma unroll
      for (int r=0; r<4; ++r){
        u16 grv = r==0?gr_.x : r==1?gr_.y : r==2?gr_.z : gr_.w;
        u16 guv = r==0?gu_.x : r==1?gu_.y : r==2?gu_.z : gu_.w;
        u16 gnv = r==0?gn_.x : r==1?gn_.y : r==2?gn_.z : gn_.w;
        float rr = sigm(bf2f(grv) + aR[r]);
        float uu = sigm(bf2f(guv) + aU[r]);
        float nn = tanh_s(bf2f(gnv) + rr*aN[r]);
        float h = nn + uu*(hprev[r]-nn);
        hprev[r] = h;
        h4[r] = h;
      }
      uint2 hpk;
      hpk.x = pk_bf16(h4[0], h4[1]);
      hpk.y = pk_bf16(h4[2], h4[3]);
      *(uint2*)((char*)hw + hwoff) = hpk;
      uint2 hst = (t < ndc) ? hpk : make_uint2(0u,0u);
      *(uint2*)(hsp + t*256) = hst;
    }
    // D: fence + single barrier
    asm volatile("s_waitcnt lgkmcnt(0)" ::: "memory");
    __builtin_amdgcn_sched_barrier(0);
    __builtin_amdgcn_s_barrier();
    __builtin_amdgcn_sched_barrier(0);
    { const u16* tmp = hr; hr = hw; hw = (u16*)tmp; }
    cur = cur==2 ? 0 : cur+1;
  }
}

// ---------------- sequential VAE scan; no global stores inside loop ----------------
// 256 blocks x 512 threads, 16 batch rows/block. HPQ m-major [B*T][256].
__global__ __launch_bounds__(512) void vae_seq(
  const u16* __restrict__ HPQ, const float* __restrict__ z0,
  const float* __restrict__ eps, const int* __restrict__ n_days,
  const u16* __restrict__ Wm,
  const float* __restrict__ bpm, const float* __restrict__ bps,
  const float* __restrict__ bqm, const float* __restrict__ bqs,
  u16* __restrict__ zidx, float* __restrict__ out)
{
  const int b0 = blockIdx.x*16;
  const int tid = threadIdx.x, w = tid>>6, lane = tid&63, c = lane&15, g = lane>>4;
  const int j0 = w*16 + g*4;                 // this thread's 4 z-dims (batch = c)
  __shared__ __align__(16) u16 zbuf[16*16*8];      // 4KB
  __shared__ __align__(16) u16 hzpb[16*16*8];
  __shared__ __align__(16) u16 hzqb[16*16*8];
  __shared__ __align__(16) char hpql[3][8192];     // swizzled [batch 16][512B]
  __shared__ __align__(16) char epsl[3][8192];     // swizzled [batch 16][512B]
  __shared__ float klb[32][16][8];                 // 16KB deferred KL partials

  bf16x8 wf[6][4];
  #pragma unroll
  for (int mat=0;mat<6;++mat)
    #pragma unroll
    for (int ks=0;ks<4;++ks)
      wf[mat][ks] = *(const bf16x8*)&Wm[mat*16384 + (w*16+c)*128 + ks*32 + g*8];

  const float4 bpm4 = *(const float4*)(bpm + j0);
  const float4 bps4 = *(const float4*)(bps + j0);
  const float4 bqm4 = *(const float4*)(bqm + j0);
  const float4 bqs4 = *(const float4*)(bqs + j0);
  const int ndc = n_days[b0 + c];

  int soH, soE;
  { int p = (w*64 + lane)*16; int row = p/512, off = p%512;
    int so = off ^ ((row&7)<<4);
    soH = (b0+row)*32*256 + (so>>1);
    soE = (b0+row)*128 + (so>>2); }
  const int rdH = c*512 + ((j0*2) ^ ((c&7)<<4));
  const int rdE = c*512 + ((j0*4) ^ ((c&7)<<4));
  const int hroff = (g*16 + c)*16;
  const int hwoff = ((w*2 + (g>>1))*16 + c)*16 + (g&1)*8;

  if (tid < 256){
    int k8 = tid>>4, row = tid&15;
    const float* zp = z0 + (size_t)(b0+row)*128 + k8*8;
    uint4 o;
    o.x = pk_bf16(zp[0], zp[1]);
    o.y = pk_bf16(zp[2], zp[3]);
    o.z = pk_bf16(zp[4], zp[5]);
    o.w = pk_bf16(zp[6], zp[7]);
    ((uint4*)zbuf)[tid] = o;
  }
  // prologue prefetch planes 0,1
  gl2lds16(HPQ + soH,        hpql[0] + w*1024);
  gl2lds16(eps + soE,        epsl[0] + w*1024);
  gl2lds16(HPQ + soH + 256,  hpql[1] + w*1024);
  gl2lds16(eps + soE + 524288, epsl[1] + w*1024);
  asm volatile("s_waitcnt vmcnt(0)" ::: "memory");
  __syncthreads();

  uint2 zsel = make_uint2(0u,0u);
  int cur = 0;
  #pragma unroll 1
  for (int t=0; t<32; ++t){
    // A: prefetch t+2
    if (t < 30){
      int nxt3 = cur >= 1 ? cur-1 : 2;
      gl2lds16(HPQ + soH + (t+2)*256,           hpql[nxt3] + w*1024);
      gl2lds16(eps + soE + (size_t)(t+2)*524288, epsl[nxt3] + w*1024);
    }
    if (t < 30)      { asm volatile("s_waitcnt vmcnt(2)" ::: "memory"); }
    else if (t == 30){ asm volatile("s_waitcnt vmcnt(0)" ::: "memory"); }
    __builtin_amdgcn_sched_barrier(0);
    // B: stage-1 MFMA (z-part of prior/posterior hidden)
    f32x4 accP = (f32x4){0,0,0,0}, accQ = (f32x4){0,0,0,0};
    #pragma unroll
    for (int ks=0;ks<4;++ks){
      bf16x8 zf = *(const bf16x8*)((const char*)zbuf + hroff + ks*1024);
      accP = mfma16(wf[0][ks], zf, accP);
      accQ = mfma16(wf[1][ks], zf, accQ);
    }
    // C: combine with staged HPQ, tanh, stage to LDS
    {
      const char* hb_ = hpql[cur];
      ushort4 hp4 = *(const ushort4*)(hb_ + rdH);
      ushort4 hq4 = *(const ushort4*)(hb_ + rdH + 256);
      float p4[4], q4[4];
      #pragma unroll
      for (int r=0;r<4;++r){
        u16 pv = r==0?hp4.x : r==1?hp4.y : r==2?hp4.z : hp4.w;
        u16 qv = r==0?hq4.x : r==1?hq4.y : r==2?hq4.z : hq4.w;
        p4[r] = tanh_s(bf2f(pv) + accP[r]);
        q4[r] = tanh_s(bf2f(qv) + accQ[r]);
      }
      uint2 ppk, qpk;
      ppk.x = pk_bf16(p4[0], p4[1]);  ppk.y = pk_bf16(p4[2], p4[3]);
      qpk.x = pk_bf16(q4[0], q4[1]);  qpk.y = pk_bf16(q4[2], q4[3]);
      *(uint2*)((char*)hzpb + hwoff) = ppk;
      *(uint2*)((char*)hzqb + hwoff) = qpk;
    }
    asm volatile("s_waitcnt lgkmcnt(0)" ::: "memory");
    __builtin_amdgcn_sched_barrier(0);
    __builtin_amdgcn_s_barrier();
    __builtin_amdgcn_sched_barrier(0);
    // D: stage-2 MFMAs + KL + z
    {
      f32x4 aMP=(f32x4){0,0,0,0}, aAP=(f32x4){0,0,0,0};
      f32x4 aMQ=(f32x4){0,0,0,0}, aAQ=(f32x4){0,0,0,0};
      #pragma unroll
      for (int ks=0;ks<4;++ks){
        bf16x8 pf = *(const bf16x8*)((const char*)hzpb + hroff + ks*1024);
        bf16x8 qf = *(const bf16x8*)((const char*)hzqb + hroff + ks*1024);
        aMP = mfma16(wf[2][ks], pf, aMP);
        aAP = mfma16(wf[3][ks], pf, aAP);
        aMQ = mfma16(wf[4][ks], qf, aMQ);
        aAQ = mfma16(wf[5][ks], qf, aAQ);
      }
      float4 e4 = *(const float4*)(epsl[cur] + rdE);
      float kls = 0.f;
      float z4[4];
      #pragma unroll
      for (int r=0;r<4;++r){
        float mp = aMP[r]+(r==0?bpm4.x:r==1?bpm4.y:r==2?bpm4.z:bpm4.w);
        float ap = aAP[r]+(r==0?bps4.x:r==1?bps4.y:r==2?bps4.z:bps4.w);
        float mq = aMQ[r]+(r==0?bqm4.x:r==1?bqm4.y:r==2?bqm4.z:bqm4.w);
        float aq = aAQ[r]+(r==0?bqs4.x:r==1?bqs4.y:r==2?bqs4.z:bqs4.w);
        float ev = r==0?e4.x : r==1?e4.y : r==2?e4.z : e4.w;
        float z = mq + __expf(0.5f*aq)*ev;
        float d = mq - mp;
        kls += 0.5f*(ap-aq) + 0.5f*(__expf(aq)+d*d)*__expf(-ap) - 0.5f;
        z4[r] = z;
      }
      uint2 zpk;
      zpk.x = pk_bf16(z4[0], z4[1]);
      zpk.y = pk_bf16(z4[2], z4[3]);
      *(uint2*)((char*)zbuf + hwoff) = zpk;
      if (t == ndc-1) zsel = zpk;          // register select, no store
      kls += __shfl_xor(kls, 16);
      kls += __shfl_xor(kls, 32);
      if (lane < 16) klb[t][c][w] = kls;   // deferred
    }
    asm volatile("s_waitcnt lgkmcnt(0)" ::: "memory");
    __builtin_amdgcn_sched_barrier(0);
    __builtin_amdgcn_s_barrier();
    __builtin_amdgcn_sched_barrier(0);
    cur = cur==2 ? 0 : cur+1;
  }
  // epilogue: zidx + kls outputs
  *(uint2*)(zidx + (size_t)(b0+c)*128 + j0) = zsel;
  {
    int t2 = tid>>4, c2 = tid&15;
    float s = 0.f;
    #pragma unroll
    for (int ww=0;ww<8;++ww) s += klb[t2][c2][ww];
    out[(size_t)(b0+c2)*162 + 130 + t2] = s;
  }
}

// ---------------- head: g_T, y_T ----------------
__global__ __launch_bounds__(128) void head_k(
  const u16* __restrict__ hs, const u16* __restrict__ zidx,
  const int* __restrict__ n_days, const u16* __restrict__ Wgb,
  const float* __restrict__ bg, const float* __restrict__ Wy,
  const float* __restrict__ by, float* __restrict__ out)
{
  const int b = blockIdx.x;
  const int tid = threadIdx.x;
  const int lane = tid & 63, wv = tid >> 6;
  __shared__ float hz[384];
  __shared__ float red[2][2];
  const int idx = n_days[b]-1;
  const u16* hrow = hs + ((size_t)b*32 + idx)*256;
  for (int k=tid; k<256; k+=128) hz[k] = bf2f(hrow[k]);
  hz[256+tid] = bf2f(zidx[(size_t)b*128 + tid]);
  __syncthreads();
  const u16* wrow = Wgb + (size_t)tid*384;
  float s = 0.f;
  #pragma unroll 4
  for (int k8=0;k8<48;++k8){
    bf16x8 wvv = *(const bf16x8*)&wrow[k8*8];
    #pragma unroll
    for (int e=0;e<8;++e) s += bf2f((u16)wvv[e]) * hz[k8*8+e];
  }
  float gv = tanh_s(s + bg[tid]);
  out[(size_t)b*162 + tid] = gv;
  float a0 = gv*Wy[tid], a1 = gv*Wy[128+tid];
  #pragma unroll
  for (int off=1; off<64; off<<=1){
    a0 += __shfl_xor(a0, off);
    a1 += __shfl_xor(a1, off);
  }
  if (lane == 0){ red[0][wv] = a0; red[1][wv] = a1; }
  __syncthreads();
  if (tid == 0){
    float l0 = by[0] + red[0][0] + red[0][1];
    float l1 = by[1] + red[1][0] + red[1][1];
    float mx = fmaxf(l0,l1);
    float e0 = __expf(l0-mx), e1 = __expf(l1-mx);
    float si = e0+e1;
    out[(size_t)b*162 + 128] = e0/si;
    out[(size_t)b*162 + 129] = e1/si;
  }
}

extern "C" void kernel_launch(void* const* d_in, const int* in_sizes, int n_in,
                              void* d_out, int out_size, void* d_ws, size_t ws_size,
                              hipStream_t stream)
{
  const float* x      = (const float*)d_in[0];
  const float* y_true = (const float*)d_in[1];
  const int*   n_days = (const int*)d_in[2];
  const float* z0     = (const float*)d_in[3];
  const float* eps    = (const float*)d_in[4];
  const float* W_ih   = (const float*)d_in[5];
  const float* W_hh   = (const float*)d_in[6];
  const float* b_ih   = (const float*)d_in[7];
  const float* b_hh   = (const float*)d_in[8];
  const float* Wph    = (const float*)d_in[9];
  const float* bph    = (const float*)d_in[10];
  const float* Woh    = (const float*)d_in[11];
  const float* boh    = (const float*)d_in[12];
  const float* Wpm    = (const float*)d_in[13];
  const float* bpm    = (const float*)d_in[14];
  const float* Wps    = (const float*)d_in[15];
  const float* bps    = (const float*)d_in[16];
  const float* Wqm    = (const float*)d_in[17];
  const float* bqm    = (const float*)d_in[18];
  const float* Wqs    = (const float*)d_in[19];
  const float* bqs    = (const float*)d_in[20];
  const float* Wg     = (const float*)d_in[21];
  const float* bg     = (const float*)d_in[22];
  const float* Wy     = (const float*)d_in[23];
  const float* by     = (const float*)d_in[24];
  (void)in_sizes; (void)n_in; (void)out_size; (void)ws_size;

  u16*   wsb = (u16*)d_ws;
  float* wsf = (float*)d_ws;
  u16* Wih_b = wsb + 0;
  u16* Whh_b = wsb + 196608;
  u16* Wc_b  = wsb + 393216;
  u16* Wz_b  = wsb + 524288;      // 6 x 128x128 mats consecutive
  u16* Wg_b  = wsb + 622592;
  float* Woy  = wsf + 335872;
  float* bpq  = wsf + 336128;
  float* bsum = wsf + 336384;
  u16* xbf   = wsb + 674304;
  u16* GI    = wsb + 34228736;    // m-major [B*T][768]
  u16* hsB   = wsb + 134892032;   // [b][t][256]
  u16* HPQ   = wsb + 168446464;   // m-major [B*T][256]
  u16* zidx  = wsb + 202000896;   // [b][128]; end ~405MB

  hipLaunchKernelGGL(prep_w, dim3(2626), dim3(256), 0, stream,
                     W_ih, W_hh, Wph, Woh, Wpm, Wps, Wqm, Wqs, Wg, bph, boh,
                     wsb, Woy, bpq);
  hipLaunchKernelGGL(prep_b, dim3(1), dim3(768), 0, stream, b_ih, b_hh, bsum);
  hipLaunchKernelGGL(prep_x, dim3(16384), dim3(256), 0, stream, x, xbf);
  hipLaunchKernelGGL(gemm_bt, dim3(1024,3), dim3(512), 0, stream,
                     xbf, xbf, 256, 256, Wih_b, bsum, GI, 768, 0,
                     (const float*)nullptr, (const float*)nullptr);
  hipLaunchKernelGGL(gru_seq, dim3(256), dim3(1024), 0, stream,
                     GI, Whh_b, b_hh, n_days, hsB);
  hipLaunchKernelGGL(gemm_bt, dim3(1024,1), dim3(512), 0, stream,
                     xbf, hsB, 256, 512, Wc_b, bpq, HPQ, 256, 1, y_true, Woy);
  hipLaunchKernelGGL(vae_seq, dim3(256), dim3(512), 0, stream,
                     HPQ, z0, eps, n_days, Wz_b, bpm, bps, bqm, bqs, zidx, (float*)d_out);
  hipLaunchKernelGGL(head_k, dim3(4096), dim3(128), 0, stream,
                     hsB, zidx, n_days, Wg_b, bg, Wy, by, (float*)d_out);
}

// Round 4
// 510.252 us; speedup vs baseline: 2.2559x; 1.0701x over previous
//
#include <hip/hip_runtime.h>

typedef unsigned short u16;
typedef short bf16x8 __attribute__((ext_vector_type(8)));
typedef float f32x4 __attribute__((ext_vector_type(4)));

__device__ __forceinline__ float bf2f(u16 v){
  union { unsigned u; float f; } x; x.u = ((unsigned)v) << 16; return x.f;
}
__device__ __forceinline__ u16 f2bf(float f){
  union { float f; unsigned u; } x; x.f = f;
  unsigned u = x.u;
  u += 0x7fffu + ((u >> 16) & 1u);
  return (u16)(u >> 16);
}
__device__ __forceinline__ unsigned pk_bf16(float lo, float hi){
  unsigned r;
  asm volatile("v_cvt_pk_bf16_f32 %0, %1, %2" : "=v"(r) : "v"(lo), "v"(hi));
  return r;
}
__device__ __forceinline__ float sigm(float x){ return 1.f/(1.f+__expf(-x)); }
__device__ __forceinline__ float tanh_s(float x){ return 1.f - 2.f/(__expf(2.f*x)+1.f); }
__device__ __forceinline__ f32x4 mfma16(bf16x8 a, bf16x8 b, f32x4 c){
  return __builtin_amdgcn_mfma_f32_16x16x32_bf16(a, b, c, 0, 0, 0);
}
__device__ __forceinline__ void gl2lds16(const void* g, void* l){
  __builtin_amdgcn_global_load_lds(
      (const __attribute__((address_space(1))) unsigned int*)g,
      (__attribute__((address_space(3))) unsigned int*)l, 16, 0, 0);
}

// ---------------- prep: weights -> bf16 (+ layout splits) ----------------
__global__ void prep_w(const float* __restrict__ W_ih, const float* __restrict__ W_hh,
                       const float* __restrict__ Wph, const float* __restrict__ Woh,
                       const float* __restrict__ Wpm, const float* __restrict__ Wps,
                       const float* __restrict__ Wqm, const float* __restrict__ Wqs,
                       const float* __restrict__ Wg,  const float* __restrict__ bph,
                       const float* __restrict__ boh,
                       u16* __restrict__ wsb, float* __restrict__ Woy, float* __restrict__ bpq)
{
  int idx = blockIdx.x*256 + threadIdx.x;
  if (idx < 196608){ wsb[idx] = f2bf(W_ih[idx]); return; }
  if (idx < 393216){ wsb[idx] = f2bf(W_hh[idx-196608]); return; }
  if (idx < 524288){ int j = idx-393216; int row = j>>9, col = j&511;
    float v = (row<128) ? Wph[row*640+col] : Woh[(row-128)*642+col];
    wsb[idx] = f2bf(v); return; }
  if (idx < 540672){ int j = idx-524288; int row=j>>7, col=j&127; wsb[idx]=f2bf(Wph[row*640+512+col]); return; }
  if (idx < 557056){ int j = idx-540672; int row=j>>7, col=j&127; wsb[idx]=f2bf(Woh[row*642+514+col]); return; }
  if (idx < 573440){ wsb[idx]=f2bf(Wpm[idx-557056]); return; }
  if (idx < 589824){ wsb[idx]=f2bf(Wps[idx-573440]); return; }
  if (idx < 606208){ wsb[idx]=f2bf(Wqm[idx-589824]); return; }
  if (idx < 622592){ wsb[idx]=f2bf(Wqs[idx-606208]); return; }
  if (idx < 671744){ wsb[idx]=f2bf(Wg[idx-622592]); return; }
  if (idx < 672000){ int j = idx-671744; int row=j>>1; Woy[j] = Woh[row*642+512+(j&1)]; return; }
  if (idx < 672256){ int j = idx-672000; bpq[j] = (j<128) ? bph[j] : boh[j-128]; return; }
}

__global__ void prep_b(const float* __restrict__ b_ih, const float* __restrict__ b_hh,
                       float* __restrict__ bsum)
{
  int j = threadIdx.x;
  if (j < 768) bsum[j] = b_ih[j] + (j < 512 ? b_hh[j] : 0.f);
}

__global__ void prep_x(const float* __restrict__ x, u16* __restrict__ xbf){
  int i = blockIdx.x*256 + threadIdx.x;
  if (i >= 4194304) return;
  const float4* src = (const float4*)(x + (size_t)i*8);
  float4 a = src[0], b = src[1];
  uint4 o;
  o.x = pk_bf16(a.x, a.y);
  o.y = pk_bf16(a.z, a.w);
  o.z = pk_bf16(b.x, b.y);
  o.w = pk_bf16(b.z, b.w);
  ((uint4*)xbf)[i] = o;
}

// ---------------- counting sort of n_days, descending ----------------
// perm[pos] = original row; nd_s[pos] = its n_days; cnt[t] = #rows with nd > t
__global__ void sort_days(const int* __restrict__ n_days, int* __restrict__ perm,
                          int* __restrict__ nd_s, int* __restrict__ cnt)
{
  __shared__ int hist[34];
  __shared__ int base[34];
  __shared__ int cursor[34];
  int tid = threadIdx.x;
  if (tid < 34) hist[tid] = 0;
  __syncthreads();
  for (int i = tid; i < 4096; i += 1024) atomicAdd(&hist[n_days[i]], 1);
  __syncthreads();
  if (tid == 0){
    int acc = 0;
    for (int v = 32; v >= 1; --v){ base[v] = acc; acc += hist[v]; }
    base[0] = acc;  // 4096
  }
  __syncthreads();
  if (tid < 33) cursor[tid] = base[tid];
  if (tid < 32) cnt[tid] = base[tid];
  __syncthreads();
  for (int i = tid; i < 4096; i += 1024){
    int v = n_days[i];
    int pos = atomicAdd(&cursor[v], 1);
    perm[pos] = i;
    nd_s[pos] = v;
  }
}

// ---------------- GI GEMM: t-major sorted, tile-skip, coalesced epilogue ----
// grid (1024, 3): bx -> t=bx>>5, rt=bx&31 ; block 512.
// GI[t][srow][768] = x[perm[srow], t] @ W_ih^T + bsum
__global__ __launch_bounds__(512, 4) void gemm_gi(
  const u16* __restrict__ A, const u16* __restrict__ W,
  const float* __restrict__ bias, const int* __restrict__ perm,
  const int* __restrict__ cnt, u16* __restrict__ C)
{
  const int t  = blockIdx.x >> 5;
  const int rt = blockIdx.x & 31;
  if (rt*128 >= cnt[t]) return;
  const int n0 = blockIdx.y*256;
  const int tid = threadIdx.x;
  const int w = tid>>6, lane = tid&63, c = lane&15, g = lane>>4;
  const int wm = w>>2, wn = w&3;
  __shared__ __align__(16) char smem[49152];
  u16* abuf = (u16*)smem;            // 16KB [k8][row128][8]
  u16* wbuf = (u16*)(smem + 16384);  // 32KB [k8][row256][8]
  u16* clds = (u16*)smem;            // epilogue alias, 128x136 u16

  size_t asrc[2];
  #pragma unroll
  for (int i=0;i<2;++i){
    int p = (w*2+i)*64 + lane;
    int k8 = p>>7, row = p&127;
    asrc[i] = ((size_t)perm[rt*128 + row]*32 + t)*256 + k8*8;
  }
  size_t wsrc[4];
  #pragma unroll
  for (int i=0;i<4;++i){
    int p = (w*4+i)*64 + lane;
    int k8 = p>>8, row = p&255;
    wsrc[i] = (size_t)(n0+row)*256 + k8*8;
  }
  f32x4 acc[4][4];
  #pragma unroll
  for (int i=0;i<4;++i)
    #pragma unroll
    for (int j=0;j<4;++j) acc[i][j] = (f32x4){0.f,0.f,0.f,0.f};
  for (int kc=0; kc<4; ++kc){
    __syncthreads();
    #pragma unroll
    for (int i=0;i<2;++i) gl2lds16(A + asrc[i] + kc*64, &abuf[(w*2+i)*512]);
    #pragma unroll
    for (int i=0;i<4;++i) gl2lds16(W + wsrc[i] + kc*64, &wbuf[(w*4+i)*512]);
    __syncthreads();
    #pragma unroll
    for (int ks=0;ks<2;++ks){
      int k8 = ks*4 + g;
      bf16x8 a[4];
      #pragma unroll
      for (int mt=0;mt<4;++mt) a[mt] = *(const bf16x8*)&abuf[(k8*128 + wm*64 + mt*16 + c)*8];
      #pragma unroll
      for (int nt=0;nt<4;++nt){
        bf16x8 b = *(const bf16x8*)&wbuf[(k8*256 + wn*64 + nt*16 + c)*8];
        #pragma unroll
        for (int mt=0;mt<4;++mt)
          acc[mt][nt] = mfma16(a[mt], b, acc[mt][nt]);
      }
    }
  }
  __syncthreads();
  const size_t crow = (size_t)t*4096 + rt*128;
  #pragma unroll
  for (int nh=0; nh<2; ++nh){
    if ((wn>>1) == nh){
      #pragma unroll
      for (int nt=0;nt<4;++nt){
        int n = n0 + wn*64 + nt*16 + c;
        float bn = bias[n];
        int lc = (wn&1)*64 + nt*16 + c;
        #pragma unroll
        for (int mt=0;mt<4;++mt){
          int lr = wm*64 + mt*16 + g*4;
          #pragma unroll
          for (int r=0;r<4;++r)
            clds[(lr+r)*136 + lc] = f2bf(acc[mt][nt][r] + bn);
        }
      }
    }
    __syncthreads();
    #pragma unroll
    for (int p=0;p<4;++p){
      int idx = p*512 + tid;
      int row = idx>>4, ch = idx&15;
      *(uint4*)(C + (crow+row)*768 + n0 + nh*128 + ch*8)
        = *(const uint4*)&clds[row*136 + ch*8];
    }
    __syncthreads();
  }
}

// ---------------- HPQ GEMM: [xbf|hsB] @ Wc^T + bpq (+ y rank-2), m-major ----
__global__ __launch_bounds__(512, 4) void gemm_hpq(
  const u16* __restrict__ A1, const u16* __restrict__ A2,
  const u16* __restrict__ W, const float* __restrict__ bias,
  const float* __restrict__ yt, const float* __restrict__ Woy,
  u16* __restrict__ C)
{
  const int m0 = blockIdx.x*128;
  const int tid = threadIdx.x;
  const int w = tid>>6, lane = tid&63, c = lane&15, g = lane>>4;
  const int wm = w>>2, wn = w&3;
  __shared__ __align__(16) char smem[49152];
  u16* abuf = (u16*)smem;
  u16* wbuf = (u16*)(smem + 16384);
  u16* clds = (u16*)smem;

  size_t asrc[2];
  #pragma unroll
  for (int i=0;i<2;++i){
    int p = (w*2+i)*64 + lane;
    int k8 = p>>7, row = p&127;
    asrc[i] = (size_t)(m0+row)*256 + k8*8;
  }
  size_t wsrc[4];
  #pragma unroll
  for (int i=0;i<4;++i){
    int p = (w*4+i)*64 + lane;
    int k8 = p>>8, row = p&255;
    wsrc[i] = (size_t)row*512 + k8*8;
  }
  f32x4 acc[4][4];
  #pragma unroll
  for (int i=0;i<4;++i)
    #pragma unroll
    for (int j=0;j<4;++j) acc[i][j] = (f32x4){0.f,0.f,0.f,0.f};
  for (int kc=0; kc<8; ++kc){
    __syncthreads();
    const u16* Ab = (kc < 4) ? A1 : A2;
    int ko = (kc & 3)*64;
    #pragma unroll
    for (int i=0;i<2;++i) gl2lds16(Ab + asrc[i] + ko, &abuf[(w*2+i)*512]);
    #pragma unroll
    for (int i=0;i<4;++i) gl2lds16(W + wsrc[i] + kc*64, &wbuf[(w*4+i)*512]);
    __syncthreads();
    #pragma unroll
    for (int ks=0;ks<2;++ks){
      int k8 = ks*4 + g;
      bf16x8 a[4];
      #pragma unroll
      for (int mt=0;mt<4;++mt) a[mt] = *(const bf16x8*)&abuf[(k8*128 + wm*64 + mt*16 + c)*8];
      #pragma unroll
      for (int nt=0;nt<4;++nt){
        bf16x8 b = *(const bf16x8*)&wbuf[(k8*256 + wn*64 + nt*16 + c)*8];
        #pragma unroll
        for (int mt=0;mt<4;++mt)
          acc[mt][nt] = mfma16(a[mt], b, acc[mt][nt]);
      }
    }
  }
  __syncthreads();
  #pragma unroll
  for (int nh=0; nh<2; ++nh){
    if ((wn>>1) == nh){
      #pragma unroll
      for (int nt=0;nt<4;++nt){
        int n = wn*64 + nt*16 + c;
        float bn = bias[n];
        float wy0 = 0.f, wy1 = 0.f;
        bool yfl = (n >= 128);
        if (yfl){ wy0 = Woy[(n-128)*2]; wy1 = Woy[(n-128)*2+1]; }
        int lc = (wn&1)*64 + nt*16 + c;
        #pragma unroll
        for (int mt=0;mt<4;++mt){
          int lr = wm*64 + mt*16 + g*4;
          #pragma unroll
          for (int r=0;r<4;++r){
            size_t m = (size_t)m0 + lr + r;
            float v = acc[mt][nt][r] + bn;
            if (yfl) v += yt[2*m]*wy0 + yt[2*m+1]*wy1;
            clds[(lr+r)*136 + lc] = f2bf(v);
          }
        }
      }
    }
    __syncthreads();
    #pragma unroll
    for (int p=0;p<4;++p){
      int idx = p*512 + tid;
      int row = idx>>4, ch = idx&15;
      *(uint4*)(C + (size_t)(m0+row)*256 + nh*128 + ch*8)
        = *(const uint4*)&clds[row*136 + ch*8];
    }
    __syncthreads();
  }
}

// ---------------- sequential GRU over T; W_hh register-resident -------------
// 256 blocks x 1024 threads, 16 SORTED batch rows/block. GI t-major sorted.
__global__ __launch_bounds__(1024, 4) void gru_seq(
  const u16* __restrict__ GI, const u16* __restrict__ Whh,
  const float* __restrict__ bhh, const int* __restrict__ perm,
  const int* __restrict__ nd_s, u16* __restrict__ hs)
{
  const int b0 = blockIdx.x*16;
  const int tid = threadIdx.x;
  const int w = tid>>6, lane = tid&63, c = lane&15, g = lane>>4;
  const int j0 = w*16 + g*4;
  __shared__ __align__(16) u16 hbuf[2][4096];
  __shared__ __align__(16) u16 gibuf[3][12288];
  __shared__ float bhnl[256];

  bf16x8 wa[3][8];
  #pragma unroll
  for (int gate=0; gate<3; ++gate)
    #pragma unroll
    for (int ks=0; ks<8; ++ks)
      wa[gate][ks] = *(const bf16x8*)&Whh[(size_t)(gate*256 + w*16 + c)*256 + ks*32 + g*8];

  if (tid < 256) bhnl[tid] = bhh[512 + tid];
  const int ndc   = nd_s[b0 + c];
  const int bound = nd_s[b0];           // descending sort -> max of block
  const int ob    = perm[b0 + c];

  int so0, so1;
  { int pe = w*512 + lane*8; int row = pe/768, off = pe - row*768;
    so0 = (b0+row)*768 + (off ^ ((row&7)<<3)); }
  { int pe = (16+w)*512 + lane*8; int row = pe/768, off = pe - row*768;
    so1 = (b0+row)*768 + (off ^ ((row&7)<<3)); }
  const int rd0 = c*1536 + ((j0*2) ^ ((c&7)<<4));
  const int hroff = (g*16 + c)*16;
  const int hwoff = ((w*2 + (g>>1))*16 + c)*16 + (g&1)*8;
  u16* hsp = hs + (size_t)ob*8192 + j0;

  float hprev[4] = {0.f,0.f,0.f,0.f};
  if (tid < 512) ((uint4*)hbuf[0])[tid] = make_uint4(0,0,0,0);

  const size_t PL = 3145728;  // 4096*768
  int p1 = (bound > 1) ? 1 : 0;
  gl2lds16(GI + so0, (char*)gibuf[0] + w*1024);
  if (w < 8) gl2lds16(GI + so1, (char*)gibuf[0] + (16+w)*1024);
  gl2lds16(GI + (size_t)p1*PL + so0, (char*)gibuf[1] + w*1024);
  if (w < 8) gl2lds16(GI + (size_t)p1*PL + so1, (char*)gibuf[1] + (16+w)*1024);
  asm volatile("s_waitcnt vmcnt(0)" ::: "memory");
  __syncthreads();

  const u16* hr = hbuf[0];
  u16*       hw = hbuf[1];
  int cur = 0;
  #pragma unroll 1
  for (int t=0; t<bound; ++t){
    // A: prefetch plane (clamped) into rotating buffer
    {
      int pf = (t+2 < bound) ? t+2 : bound-1;
      int nxt3 = cur >= 1 ? cur-1 : 2;
      gl2lds16(GI + (size_t)pf*PL + so0, (char*)gibuf[nxt3] + w*1024);
      if (w < 8) gl2lds16(GI + (size_t)pf*PL + so1, (char*)gibuf[nxt3] + (16+w)*1024);
    }
    // hoisted gate reads: plane t guaranteed by previous barrier
    const char* gib = (const char*)gibuf[cur];
    ushort4 gr_ = *(const ushort4*)(gib + rd0);
    ushort4 gu_ = *(const ushort4*)(gib + rd0 + 512);
    ushort4 gn_ = *(const ushort4*)(gib + rd0 + 1024);
    if (w < 8) asm volatile("s_waitcnt vmcnt(3)" ::: "memory");
    else       asm volatile("s_waitcnt vmcnt(2)" ::: "memory");
    __builtin_amdgcn_sched_barrier(0);
    // B: MFMA (gh^T: D[Wrow][batch])
    f32x4 aR = (f32x4){0.f,0.f,0.f,0.f};
    f32x4 aU = (f32x4){0.f,0.f,0.f,0.f};
    float4 bhn4 = *(const float4*)&bhnl[j0];
    f32x4 aN = (f32x4){bhn4.x, bhn4.y, bhn4.z, bhn4.w};
    __builtin_amdgcn_s_setprio(1);
    #pragma unroll
    for (int ks=0; ks<8; ++ks){
      bf16x8 hf = *(const bf16x8*)((const char*)hr + hroff + ks*1024);
      aR = mfma16(wa[0][ks], hf, aR);
      aU = mfma16(wa[1][ks], hf, aU);
      aN = mfma16(wa[2][ks], hf, aN);
    }
    __builtin_amdgcn_s_setprio(0);
    // C: gates
    {
      float h4[4];
      #pragma unroll
      for (int r=0; r<4; ++r){
        u16 grv = r==0?gr_.x : r==1?gr_.y : r==2?gr_.z : gr_.w;
        u16 guv = r==0?gu_.x : r==1?gu_.y : r==2?gu_.z : gu_.w;
        u16 gnv = r==0?gn_.x : r==1?gn_.y : r==2?gn_.z : gn_.w;
        float rr = sigm(bf2f(grv) + aR[r]);
        float uu = sigm(bf2f(guv) + aU[r]);
        float nn = tanh_s(bf2f(gnv) + rr*aN[r]);
        float h = nn + uu*(hprev[r]-nn);
        hprev[r] = h;
        h4[r] = h;
      }
      uint2 hpk;
      hpk.x = pk_bf16(h4[0], h4[1]);
      hpk.y = pk_bf16(h4[2], h4[3]);
      *(uint2*)((char*)hw + hwoff) = hpk;
      uint2 hst = (t < ndc) ? hpk : make_uint2(0u,0u);
      *(uint2*)(hsp + t*256) = hst;
    }
    // D: fence + single barrier
    asm volatile("s_waitcnt lgkmcnt(0)" ::: "memory");
    __builtin_amdgcn_sched_barrier(0);
    __builtin_amdgcn_s_barrier();
    __builtin_amdgcn_sched_barrier(0);
    { const u16* tmp = hr; hr = hw; hw = (u16*)tmp; }
    cur = cur==2 ? 0 : cur+1;
  }
  // zero-fill tail of hs (rows never reached)
  for (int t=bound; t<32; ++t)
    *(uint2*)(hsp + t*256) = make_uint2(0u,0u);
}

// ---------------- sequential VAE scan; no global stores inside loop ---------
__global__ __launch_bounds__(512) void vae_seq(
  const u16* __restrict__ HPQ, const float* __restrict__ z0,
  const float* __restrict__ eps, const int* __restrict__ n_days,
  const u16* __restrict__ Wm,
  const float* __restrict__ bpm, const float* __restrict__ bps,
  const float* __restrict__ bqm, const float* __restrict__ bqs,
  u16* __restrict__ zidx, float* __restrict__ out)
{
  const int b0 = blockIdx.x*16;
  const int tid = threadIdx.x, w = tid>>6, lane = tid&63, c = lane&15, g = lane>>4;
  const int j0 = w*16 + g*4;
  __shared__ __align__(16) u16 zbuf[16*16*8];
  __shared__ __align__(16) u16 hzpb[16*16*8];
  __shared__ __align__(16) u16 hzqb[16*16*8];
  __shared__ __align__(16) char hpql[3][8192];
  __shared__ __align__(16) char epsl[3][8192];
  __shared__ float klb[32][16][8];

  bf16x8 wf[6][4];
  #pragma unroll
  for (int mat=0;mat<6;++mat)
    #pragma unroll
    for (int ks=0;ks<4;++ks)
      wf[mat][ks] = *(const bf16x8*)&Wm[mat*16384 + (w*16+c)*128 + ks*32 + g*8];

  const float4 bpm4 = *(const float4*)(bpm + j0);
  const float4 bps4 = *(const float4*)(bps + j0);
  const float4 bqm4 = *(const float4*)(bqm + j0);
  const float4 bqs4 = *(const float4*)(bqs + j0);
  const int ndc = n_days[b0 + c];

  int soH, soE;
  { int p = (w*64 + lane)*16; int row = p/512, off = p%512;
    int so = off ^ ((row&7)<<4);
    soH = (b0+row)*32*256 + (so>>1);
    soE = (b0+row)*128 + (so>>2); }
  const int rdH = c*512 + ((j0*2) ^ ((c&7)<<4));
  const int rdE = c*512 + ((j0*4) ^ ((c&7)<<4));
  const int hroff = (g*16 + c)*16;
  const int hwoff = ((w*2 + (g>>1))*16 + c)*16 + (g&1)*8;

  if (tid < 256){
    int k8 = tid>>4, row = tid&15;
    const float* zp = z0 + (size_t)(b0+row)*128 + k8*8;
    uint4 o;
    o.x = pk_bf16(zp[0], zp[1]);
    o.y = pk_bf16(zp[2], zp[3]);
    o.z = pk_bf16(zp[4], zp[5]);
    o.w = pk_bf16(zp[6], zp[7]);
    ((uint4*)zbuf)[tid] = o;
  }
  gl2lds16(HPQ + soH,          hpql[0] + w*1024);
  gl2lds16(eps + soE,          epsl[0] + w*1024);
  gl2lds16(HPQ + soH + 256,    hpql[1] + w*1024);
  gl2lds16(eps + soE + 524288, epsl[1] + w*1024);
  asm volatile("s_waitcnt vmcnt(0)" ::: "memory");
  __syncthreads();

  uint2 zsel = make_uint2(0u,0u);
  int cur = 0;
  #pragma unroll 1
  for (int t=0; t<32; ++t){
    if (t < 30){
      int nxt3 = cur >= 1 ? cur-1 : 2;
      gl2lds16(HPQ + soH + (t+2)*256,            hpql[nxt3] + w*1024);
      gl2lds16(eps + soE + (size_t)(t+2)*524288, epsl[nxt3] + w*1024);
    }
    if (t < 30)      { asm volatile("s_waitcnt vmcnt(2)" ::: "memory"); }
    else if (t == 30){ asm volatile("s_waitcnt vmcnt(0)" ::: "memory"); }
    __builtin_amdgcn_sched_barrier(0);
    f32x4 accP = (f32x4){0,0,0,0}, accQ = (f32x4){0,0,0,0};
    #pragma unroll
    for (int ks=0;ks<4;++ks){
      bf16x8 zf = *(const bf16x8*)((const char*)zbuf + hroff + ks*1024);
      accP = mfma16(wf[0][ks], zf, accP);
      accQ = mfma16(wf[1][ks], zf, accQ);
    }
    {
      const char* hb_ = hpql[cur];
      ushort4 hp4 = *(const ushort4*)(hb_ + rdH);
      ushort4 hq4 = *(const ushort4*)(hb_ + rdH + 256);
      float p4[4], q4[4];
      #pragma unroll
      for (int r=0;r<4;++r){
        u16 pv = r==0?hp4.x : r==1?hp4.y : r==2?hp4.z : hp4.w;
        u16 qv = r==0?hq4.x : r==1?hq4.y : r==2?hq4.z : hq4.w;
        p4[r] = tanh_s(bf2f(pv) + accP[r]);
        q4[r] = tanh_s(bf2f(qv) + accQ[r]);
      }
      uint2 ppk, qpk;
      ppk.x = pk_bf16(p4[0], p4[1]);  ppk.y = pk_bf16(p4[2], p4[3]);
      qpk.x = pk_bf16(q4[0], q4[1]);  qpk.y = pk_bf16(q4[2], q4[3]);
      *(uint2*)((char*)hzpb + hwoff) = ppk;
      *(uint2*)((char*)hzqb + hwoff) = qpk;
    }
    asm volatile("s_waitcnt lgkmcnt(0)" ::: "memory");
    __builtin_amdgcn_sched_barrier(0);
    __builtin_amdgcn_s_barrier();
    __builtin_amdgcn_sched_barrier(0);
    {
      f32x4 aMP=(f32x4){0,0,0,0}, aAP=(f32x4){0,0,0,0};
      f32x4 aMQ=(f32x4){0,0,0,0}, aAQ=(f32x4){0,0,0,0};
      #pragma unroll
      for (int ks=0;ks<4;++ks){
        bf16x8 pf = *(const bf16x8*)((const char*)hzpb + hroff + ks*1024);
        bf16x8 qf = *(const bf16x8*)((const char*)hzqb + hroff + ks*1024);
        aMP = mfma16(wf[2][ks], pf, aMP);
        aAP = mfma16(wf[3][ks], pf, aAP);
        aMQ = mfma16(wf[4][ks], qf, aMQ);
        aAQ = mfma16(wf[5][ks], qf, aAQ);
      }
      float4 e4 = *(const float4*)(epsl[cur] + rdE);
      float kls = 0.f;
      float z4[4];
      #pragma unroll
      for (int r=0;r<4;++r){
        float mp = aMP[r]+(r==0?bpm4.x:r==1?bpm4.y:r==2?bpm4.z:bpm4.w);
        float ap = aAP[r]+(r==0?bps4.x:r==1?bps4.y:r==2?bps4.z:bps4.w);
        float mq = aMQ[r]+(r==0?bqm4.x:r==1?bqm4.y:r==2?bqm4.z:bqm4.w);
        float aq = aAQ[r]+(r==0?bqs4.x:r==1?bqs4.y:r==2?bqs4.z:bqs4.w);
        float ev = r==0?e4.x : r==1?e4.y : r==2?e4.z : e4.w;
        float z = mq + __expf(0.5f*aq)*ev;
        float d = mq - mp;
        kls += 0.5f*(ap-aq) + 0.5f*(__expf(aq)+d*d)*__expf(-ap) - 0.5f;
        z4[r] = z;
      }
      uint2 zpk;
      zpk.x = pk_bf16(z4[0], z4[1]);
      zpk.y = pk_bf16(z4[2], z4[3]);
      *(uint2*)((char*)zbuf + hwoff) = zpk;
      if (t == ndc-1) zsel = zpk;
      kls += __shfl_xor(kls, 16);
      kls += __shfl_xor(kls, 32);
      if (lane < 16) klb[t][c][w] = kls;
    }
    asm volatile("s_waitcnt lgkmcnt(0)" ::: "memory");
    __builtin_amdgcn_sched_barrier(0);
    __builtin_amdgcn_s_barrier();
    __builtin_amdgcn_sched_barrier(0);
    cur = cur==2 ? 0 : cur+1;
  }
  *(uint2*)(zidx + (size_t)(b0+c)*128 + j0) = zsel;
  {
    int t2 = tid>>4, c2 = tid&15;
    float s = 0.f;
    #pragma unroll
    for (int ww=0;ww<8;++ww) s += klb[t2][c2][ww];
    out[(size_t)(b0+c2)*162 + 130 + t2] = s;
  }
}

// ---------------- head: g_T, y_T ----------------
__global__ __launch_bounds__(128) void head_k(
  const u16* __restrict__ hs, const u16* __restrict__ zidx,
  const int* __restrict__ n_days, const u16* __restrict__ Wgb,
  const float* __restrict__ bg, const float* __restrict__ Wy,
  const float* __restrict__ by, float* __restrict__ out)
{
  const int b = blockIdx.x;
  const int tid = threadIdx.x;
  const int lane = tid & 63, wv = tid >> 6;
  __shared__ float hz[384];
  __shared__ float red[2][2];
  const int idx = n_days[b]-1;
  const u16* hrow = hs + ((size_t)b*32 + idx)*256;
  for (int k=tid; k<256; k+=128) hz[k] = bf2f(hrow[k]);
  hz[256+tid] = bf2f(zidx[(size_t)b*128 + tid]);
  __syncthreads();
  const u16* wrow = Wgb + (size_t)tid*384;
  float s = 0.f;
  #pragma unroll 4
  for (int k8=0;k8<48;++k8){
    bf16x8 wvv = *(const bf16x8*)&wrow[k8*8];
    #pragma unroll
    for (int e=0;e<8;++e) s += bf2f((u16)wvv[e]) * hz[k8*8+e];
  }
  float gv = tanh_s(s + bg[tid]);
  out[(size_t)b*162 + tid] = gv;
  float a0 = gv*Wy[tid], a1 = gv*Wy[128+tid];
  #pragma unroll
  for (int off=1; off<64; off<<=1){
    a0 += __shfl_xor(a0, off);
    a1 += __shfl_xor(a1, off);
  }
  if (lane == 0){ red[0][wv] = a0; red[1][wv] = a1; }
  __syncthreads();
  if (tid == 0){
    float l0 = by[0] + red[0][0] + red[0][1];
    float l1 = by[1] + red[1][0] + red[1][1];
    float mx = fmaxf(l0,l1);
    float e0 = __expf(l0-mx), e1 = __expf(l1-mx);
    float si = e0+e1;
    out[(size_t)b*162 + 128] = e0/si;
    out[(size_t)b*162 + 129] = e1/si;
  }
}

extern "C" void kernel_launch(void* const* d_in, const int* in_sizes, int n_in,
                              void* d_out, int out_size, void* d_ws, size_t ws_size,
                              hipStream_t stream)
{
  const float* x      = (const float*)d_in[0];
  const float* y_true = (const float*)d_in[1];
  const int*   n_days = (const int*)d_in[2];
  const float* z0     = (const float*)d_in[3];
  const float* eps    = (const float*)d_in[4];
  const float* W_ih   = (const float*)d_in[5];
  const float* W_hh   = (const float*)d_in[6];
  const float* b_ih   = (const float*)d_in[7];
  const float* b_hh   = (const float*)d_in[8];
  const float* Wph    = (const float*)d_in[9];
  const float* bph    = (const float*)d_in[10];
  const float* Woh    = (const float*)d_in[11];
  const float* boh    = (const float*)d_in[12];
  const float* Wpm    = (const float*)d_in[13];
  const float* bpm    = (const float*)d_in[14];
  const float* Wps    = (const float*)d_in[15];
  const float* bps    = (const float*)d_in[16];
  const float* Wqm    = (const float*)d_in[17];
  const float* bqm    = (const float*)d_in[18];
  const float* Wqs    = (const float*)d_in[19];
  const float* bqs    = (const float*)d_in[20];
  const float* Wg     = (const float*)d_in[21];
  const float* bg     = (const float*)d_in[22];
  const float* Wy     = (const float*)d_in[23];
  const float* by     = (const float*)d_in[24];
  (void)in_sizes; (void)n_in; (void)out_size; (void)ws_size;

  u16*   wsb = (u16*)d_ws;
  float* wsf = (float*)d_ws;
  int*   wsi = (int*)d_ws;
  u16* Wih_b = wsb + 0;
  u16* Whh_b = wsb + 196608;
  u16* Wc_b  = wsb + 393216;
  u16* Wz_b  = wsb + 524288;
  u16* Wg_b  = wsb + 622592;
  float* Woy  = wsf + 335872;
  float* bpq  = wsf + 336128;
  float* bsum = wsf + 336384;
  int* perm   = wsi + 337152;
  int* nd_s   = wsi + 341248;
  int* cnt    = wsi + 345344;
  u16* xbf   = wsb + 690752;      // [b][t][256] m-major
  u16* GI    = wsb + 34245184;    // t-major sorted [32][4096][768]
  u16* hsB   = wsb + 134908480;   // [b][t][256] original order
  u16* HPQ   = wsb + 168462912;   // m-major [B*T][256]
  u16* zidx  = wsb + 202017344;   // [b][128]; end ~405MB

  hipLaunchKernelGGL(prep_w, dim3(2626), dim3(256), 0, stream,
                     W_ih, W_hh, Wph, Woh, Wpm, Wps, Wqm, Wqs, Wg, bph, boh,
                     wsb, Woy, bpq);
  hipLaunchKernelGGL(prep_b, dim3(1), dim3(768), 0, stream, b_ih, b_hh, bsum);
  hipLaunchKernelGGL(prep_x, dim3(16384), dim3(256), 0, stream, x, xbf);
  hipLaunchKernelGGL(sort_days, dim3(1), dim3(1024), 0, stream,
                     n_days, perm, nd_s, cnt);
  hipLaunchKernelGGL(gemm_gi, dim3(1024,3), dim3(512), 0, stream,
                     xbf, Wih_b, bsum, perm, cnt, GI);
  hipLaunchKernelGGL(gru_seq, dim3(256), dim3(1024), 0, stream,
                     GI, Whh_b, b_hh, perm, nd_s, hsB);
  hipLaunchKernelGGL(gemm_hpq, dim3(1024), dim3(512), 0, stream,
                     xbf, hsB, Wc_b, bpq, y_true, Woy, HPQ);
  hipLaunchKernelGGL(vae_seq, dim3(256), dim3(512), 0, stream,
                     HPQ, z0, eps, n_days, Wz_b, bpm, bps, bqm, bqs, zidx, (float*)d_out);
  hipLaunchKernelGGL(head_k, dim3(4096), dim3(128), 0, stream,
                     hsB, zidx, n_days, Wg_b, bg, Wy, by, (float*)d_out);
}